// Round 2
// baseline (6124.490 us; speedup 1.0000x reference)
//
#include <hip/hip_runtime.h>
#include <math.h>

#define HW 4096
#define NB 256

__device__ __forceinline__ float gelu_f(float x) {
    return 0.5f * x * (1.0f + erff(x * 0.70710678118654752440f));
}

// ---------------------------------------------------------------------------
// Gaussian center window: g = exp(-(yy^2+xx^2)/(2*0.5^2)) / sum
// ---------------------------------------------------------------------------
__global__ __launch_bounds__(256) void gauss_kernel(float* __restrict__ gauss) {
    __shared__ float sg[HW];
    __shared__ float sR[4];
    int tid = threadIdx.x;
    float part = 0.0f;
    for (int p = tid; p < HW; p += 256) {
        int y = p >> 6, x = p & 63;
        float yy = -1.0f + (2.0f / 63.0f) * (float)y;
        float xx = -1.0f + (2.0f / 63.0f) * (float)x;
        float g = expf(-(yy * yy + xx * xx) * 2.0f);
        sg[p] = g;
        part += g;
    }
#pragma unroll
    for (int off = 32; off > 0; off >>= 1) part += __shfl_down(part, off);
    if ((tid & 63) == 0) sR[tid >> 6] = part;
    __syncthreads();
    float invt = 1.0f / (sR[0] + sR[1] + sR[2] + sR[3]);
    for (int p = tid; p < HW; p += 256) gauss[p] = sg[p] * invt;
}

// ---------------------------------------------------------------------------
// 3x3 SAME conv. Input is the PREVIOUS layer's raw conv output; GN+GELU of the
// previous layer is applied on load as gelu(a*x+b) with per-(b,c) coefs.
// Writes raw conv output + per-strip GN partial stats (deterministic, no atomics).
// Block: 256 thr = 4 waves, wave = one row of 64. Grid: (16 strips, bc).
// ALL pointers are pre-offset by the host for the current batch chunk;
// blockIdx.y is the LOCAL batch index.
// ---------------------------------------------------------------------------
template <int CIN, bool ACT>
__global__ __launch_bounds__(256) void conv3x3_kernel(
    const float* __restrict__ in, const float* __restrict__ coef,
    const float* __restrict__ w, float* __restrict__ out,
    float* __restrict__ statp) {
    const int b = blockIdx.y;
    const int strip = blockIdx.x;
    const int tid = threadIdx.x;
    const int x = tid & 63;
    const int wid = tid >> 6;

    __shared__ float sIn[CIN][6][66];
    __shared__ float sRed[4][8];

    const float* inb = in + (size_t)b * CIN * HW;
    for (int idx = tid; idx < CIN * 6 * 66; idx += 256) {
        int ci = idx / (6 * 66);
        int rem = idx - ci * (6 * 66);
        int r = rem / 66;
        int p = rem - r * 66;
        int gy = strip * 4 - 1 + r;
        int gx = p - 1;
        float v = 0.0f;
        if (gy >= 0 && gy < 64 && gx >= 0 && gx < 64) {
            v = inb[ci * HW + gy * 64 + gx];
            if (ACT) {
                float a = coef[(b * CIN + ci) * 2 + 0];
                float bb = coef[(b * CIN + ci) * 2 + 1];
                v = gelu_f(fmaf(a, v, bb));
            }
        }
        sIn[ci][r][p] = v;
    }
    __syncthreads();

    float acc[32];
#pragma unroll
    for (int co = 0; co < 32; ++co) acc[co] = 0.0f;

    for (int ci = 0; ci < CIN; ++ci) {
        float vv[9];
#pragma unroll
        for (int ky = 0; ky < 3; ++ky)
#pragma unroll
            for (int kx = 0; kx < 3; ++kx) vv[ky * 3 + kx] = sIn[ci][wid + ky][x + kx];
#pragma unroll
        for (int co = 0; co < 32; ++co) {
            const float* wk = w + ((size_t)co * CIN + ci) * 9;
            float s = acc[co];
#pragma unroll
            for (int k = 0; k < 9; ++k) s = fmaf(wk[k], vv[k], s);
            acc[co] = s;
        }
    }

    const int gy = strip * 4 + wid;
    float* outb = out + (size_t)b * 32 * HW + gy * 64 + x;
    float s1[4] = {0, 0, 0, 0}, s2[4] = {0, 0, 0, 0};
#pragma unroll
    for (int co = 0; co < 32; ++co) {
        float v = acc[co];
        outb[(size_t)co * HW] = v;
        s1[co >> 3] += v;
        s2[co >> 3] = fmaf(v, v, s2[co >> 3]);
    }
#pragma unroll
    for (int off = 32; off > 0; off >>= 1) {
#pragma unroll
        for (int g = 0; g < 4; ++g) {
            s1[g] += __shfl_down(s1[g], off);
            s2[g] += __shfl_down(s2[g], off);
        }
    }
    if ((tid & 63) == 0) {
#pragma unroll
        for (int g = 0; g < 4; ++g) {
            sRed[wid][g] = s1[g];
            sRed[wid][4 + g] = s2[g];
        }
    }
    __syncthreads();
    if (tid < 8) {
        float t = sRed[0][tid] + sRed[1][tid] + sRed[2][tid] + sRed[3][tid];
        statp[((size_t)b * 16 + strip) * 8 + tid] = t;
    }
}

// ---------------------------------------------------------------------------
// Reduce per-strip stats -> per-(b,c) affine coefs: y = a*x + b
// a = rstd*gamma, b = beta - mean*a.   Thread per local (b,c); n = bc*32.
// ---------------------------------------------------------------------------
__global__ __launch_bounds__(256) void gn_finalize_kernel(
    const float* __restrict__ statp, const float* __restrict__ gma,
    const float* __restrict__ bta, float* __restrict__ coef, int n) {
    int i = blockIdx.x * 256 + threadIdx.x;
    if (i >= n) return;
    int b = i >> 5, c = i & 31, g = c >> 3;
    float s1 = 0.0f, s2 = 0.0f;
    for (int s = 0; s < 16; ++s) {
        s1 += statp[((size_t)b * 16 + s) * 8 + g];
        s2 += statp[((size_t)b * 16 + s) * 8 + 4 + g];
    }
    const float invN = 1.0f / 32768.0f;
    float mean = s1 * invN;
    float var = s2 * invN - mean * mean;
    float rstd = rsqrtf(var + 1e-5f);
    float a = rstd * gma[c];
    float bb = bta[c] - mean * a;
    coef[i * 2 + 0] = a;
    coef[i * 2 + 1] = bb;
}

// ---------------------------------------------------------------------------
// Gauss-weighted pool of the activated final feature: rp[b,c] = sum feat*gauss
// Block per local (b,c). Grid (32, bc).
// ---------------------------------------------------------------------------
__global__ __launch_bounds__(256) void pool_kernel(
    const float* __restrict__ raw, const float* __restrict__ coef,
    const float* __restrict__ gauss, float* __restrict__ outp) {
    int b = blockIdx.y, c = blockIdx.x, tid = threadIdx.x;
    __shared__ float sR[4];
    float a = coef[(b * 32 + c) * 2 + 0], bb = coef[(b * 32 + c) * 2 + 1];
    const float* rb = raw + ((size_t)b * 32 + c) * HW;
    float s = 0.0f;
    for (int p = tid; p < HW; p += 256) s += gelu_f(fmaf(a, rb[p], bb)) * gauss[p];
#pragma unroll
    for (int off = 32; off > 0; off >>= 1) s += __shfl_down(s, off);
    if ((tid & 63) == 0) sR[tid >> 6] = s;
    __syncthreads();
    if (tid == 0) outp[b * 32 + c] = sR[0] + sR[1] + sR[2] + sR[3];
}

// ---------------------------------------------------------------------------
// Per-pixel: feat = gelu(a*raw+b); o = proj @ feat; n = o/max(|o|,1e-6).
// For rubin also emits energy E[b,p] and per-chunk partial sums of e*gauss.
// Grid (16 pixel-chunks, bc), thread per pixel.
// ---------------------------------------------------------------------------
__global__ __launch_bounds__(256) void proj_kernel(
    const float* __restrict__ raw, const float* __restrict__ coef,
    const float* __restrict__ pw, float* __restrict__ outn,
    float* __restrict__ E, float* __restrict__ swp,
    const float* __restrict__ gauss) {
    int b = blockIdx.y, chunk = blockIdx.x, tid = threadIdx.x;
    int p = chunk * 256 + tid;
    __shared__ float sR[4];
    const float* rb = raw + (size_t)b * 32 * HW + p;
    float v[32];
#pragma unroll
    for (int c = 0; c < 32; ++c) {
        float a = coef[(b * 32 + c) * 2 + 0], bb = coef[(b * 32 + c) * 2 + 1];
        v[c] = gelu_f(fmaf(a, rb[(size_t)c * HW], bb));
    }
    float o[32];
#pragma unroll
    for (int oo = 0; oo < 32; ++oo) o[oo] = 0.0f;
    for (int c = 0; c < 32; ++c) {
#pragma unroll
        for (int oo = 0; oo < 32; ++oo) o[oo] = fmaf(pw[oo * 32 + c], v[c], o[oo]);
    }
    float nn = 0.0f;
#pragma unroll
    for (int oo = 0; oo < 32; ++oo) nn = fmaf(o[oo], o[oo], nn);
    float n = sqrtf(nn);
    float inv = 1.0f / fmaxf(n, 1e-6f);
    float* ob = outn + (size_t)b * 32 * HW + p;
#pragma unroll
    for (int oo = 0; oo < 32; ++oo) ob[(size_t)oo * HW] = o[oo] * inv;
    if (E != nullptr) {
        float e = nn * inv * inv;
        E[(size_t)b * HW + p] = e;
        float wv = e * gauss[p];
#pragma unroll
        for (int off = 32; off > 0; off >>= 1) wv += __shfl_down(wv, off);
        if ((tid & 63) == 0) sR[tid >> 6] = wv;
        __syncthreads();
        if (tid == 0) swp[b * 16 + chunk] = sR[0] + sR[1] + sR[2] + sR[3];
    }
}

// ---------------------------------------------------------------------------
// E <- E * gauss * scale / (sum_p(E*gauss) + 1e-8)    (scale = 1/sqrt(32))
// ---------------------------------------------------------------------------
__global__ __launch_bounds__(256) void swapply_kernel(
    float* __restrict__ E, const float* __restrict__ swp,
    const float* __restrict__ gauss) {
    int b = blockIdx.y, p = blockIdx.x * 256 + threadIdx.x;
    float s = 0.0f;
#pragma unroll
    for (int i = 0; i < 16; ++i) s += swp[b * 16 + i];
    const float scale = 0.17677669529663688f;
    E[(size_t)b * HW + p] = E[(size_t)b * HW + p] * gauss[p] * scale / (s + 1e-8f);
}

// ---------------------------------------------------------------------------
// 49-offset correlation logits. Block per local b. Per (channel, y-half):
// stage 38 edge-clamped vis rows (stride 76, 16B aligned); each thread owns
// one 8-px group; all dx shifts come from a 16-float register window.
// LDS: 38*76*4 + 4*49*4 = 12.3 KiB.
// ---------------------------------------------------------------------------
__global__ __launch_bounds__(256) void logits_kernel(
    const float* __restrict__ rn, const float* __restrict__ vn,
    const float* __restrict__ sw, float* __restrict__ logits) {
    int b = blockIdx.x, tid = threadIdx.x;
    __shared__ float P[38][76];
    __shared__ float sR[4][49];
    float acc[49];
#pragma unroll
    for (int k = 0; k < 49; ++k) acc[k] = 0.0f;
    const float* swb = sw + (size_t)b * HW;
    for (int c = 0; c < 32; ++c) {
        const float* vb = vn + ((size_t)b * 32 + c) * HW;
        const float* rb = rn + ((size_t)b * 32 + c) * HW;
#pragma unroll 1
        for (int half = 0; half < 2; ++half) {
            const int base = half * 32;
            __syncthreads();  // protect P from previous iteration's readers
            for (int idx = tid; idx < 38 * 72; idx += 256) {
                int r = idx / 72, j = idx - r * 72;
                int gy = base - 3 + r;
                gy = gy < 0 ? 0 : (gy > 63 ? 63 : gy);
                int gx = j - 4;
                gx = gx < 0 ? 0 : (gx > 63 ? 63 : gx);
                P[r][j] = vb[gy * 64 + gx];
            }
            __syncthreads();
            int y = tid >> 3, x0 = (tid & 7) * 8;
            int pbase = (base + y) * 64 + x0;
            float4 r0 = *(const float4*)(rb + pbase);
            float4 r1 = *(const float4*)(rb + pbase + 4);
            float4 q0 = *(const float4*)(swb + pbase);
            float4 q1 = *(const float4*)(swb + pbase + 4);
            float r[8];
            r[0] = r0.x * q0.x; r[1] = r0.y * q0.y; r[2] = r0.z * q0.z; r[3] = r0.w * q0.w;
            r[4] = r1.x * q1.x; r[5] = r1.y * q1.y; r[6] = r1.z * q1.z; r[7] = r1.w * q1.w;
#pragma unroll
            for (int dy = 0; dy < 7; ++dy) {
                const float4* Pr = (const float4*)(&P[y + dy][x0]);
                float4 a0 = Pr[0], a1 = Pr[1], a2 = Pr[2], a3 = Pr[3];
                float v[16] = {a0.x, a0.y, a0.z, a0.w, a1.x, a1.y, a1.z, a1.w,
                               a2.x, a2.y, a2.z, a2.w, a3.x, a3.y, a3.z, a3.w};
#pragma unroll
                for (int dx = 0; dx < 7; ++dx) {
#pragma unroll
                    for (int j = 0; j < 8; ++j)
                        acc[dy * 7 + dx] = fmaf(r[j], v[j + dx + 1], acc[dy * 7 + dx]);
                }
            }
        }
    }
#pragma unroll
    for (int k = 0; k < 49; ++k) {
#pragma unroll
        for (int off = 32; off > 0; off >>= 1) acc[k] += __shfl_down(acc[k], off);
    }
    int wid = tid >> 6;
    __syncthreads();
    if ((tid & 63) == 0) {
#pragma unroll
        for (int k = 0; k < 49; ++k) sR[wid][k] = acc[k];
    }
    __syncthreads();
    if (tid < 49)
        logits[b * 49 + tid] = sR[0][tid] + sR[1][tid] + sR[2][tid] + sR[3][tid];
}

// ---------------------------------------------------------------------------
// Softmax/coarse + MLP head + output assembly. Block per b (full batch).
// Out layout per b (54): [dx, dy, sky0, sky1, log_sigma, logits(49)]
// ---------------------------------------------------------------------------
__global__ __launch_bounds__(128) void head_kernel(
    const float* __restrict__ lg, const float* __restrict__ rp,
    const float* __restrict__ vp, const float* __restrict__ p2s,
    const float* __restrict__ log_temp,
    const float* __restrict__ W1, const float* __restrict__ b1,
    const float* __restrict__ W2, const float* __restrict__ b2,
    const float* __restrict__ W3, const float* __restrict__ b3,
    float* __restrict__ out) {
    int b = blockIdx.x, t = threadIdx.x;
    __shared__ float pooled[98];
    __shared__ float h1[128], h2[128];
    __shared__ float cxy[2];
    __shared__ float res[3];
    const float* lgb = lg + b * 49;
    if (t == 0) {
        float temp = fmaxf(expf(log_temp[0]), 0.001f);
        float invT = 1.0f / temp;
        float m = -1e30f;
        for (int k = 0; k < 49; ++k) m = fmaxf(m, lgb[k] * invT);
        float s = 0.0f, pdx = 0.0f, pdy = 0.0f;
        for (int k = 0; k < 49; ++k) {
            float e = expf(lgb[k] * invT - m);
            s += e;
            pdx += e * (float)((k % 7) - 3);
            pdy += e * (float)((k / 7) - 3);
        }
        cxy[0] = pdx / s;
        cxy[1] = pdy / s;
    }
    __syncthreads();
    if (t < 32) {
        float a = rp[b * 32 + t], c = vp[b * 32 + t];
        pooled[t] = a;
        pooled[32 + t] = c;
        pooled[64 + t] = a - c;
    }
    if (t == 0) {
        pooled[96] = cxy[0];
        pooled[97] = cxy[1];
    }
    __syncthreads();
    float s1 = b1[t];
    for (int i = 0; i < 98; ++i) s1 = fmaf(pooled[i], W1[i * 128 + t], s1);
    h1[t] = gelu_f(s1);
    __syncthreads();
    float s2 = b2[t];
    for (int i = 0; i < 128; ++i) s2 = fmaf(h1[i], W2[i * 128 + t], s2);
    h2[t] = gelu_f(s2);
    __syncthreads();
    if (t < 3) {
        float r = b3[t];
        for (int i = 0; i < 128; ++i) r = fmaf(h2[i], W3[i * 3 + t], r);
        res[t] = r;
    }
    __syncthreads();
    if (t == 0) {
        float dxp = cxy[0] + res[0];
        float dyp = cxy[1] + res[1];
        float ls = fminf(fmaxf(res[2], -6.0f), 3.0f);
        const float* M = p2s + b * 4;
        float* ob = out + b * 54;
        ob[0] = dxp;
        ob[1] = dyp;
        ob[2] = M[0] * dxp + M[1] * dyp;
        ob[3] = M[2] * dxp + M[3] * dyp;
        ob[4] = ls;
    }
    if (t < 49) out[b * 54 + 5 + t] = lgb[t];
}

extern "C" void kernel_launch(void* const* d_in, const int* in_sizes, int n_in,
                              void* d_out, int out_size, void* d_ws, size_t ws_size,
                              hipStream_t stream) {
    (void)in_sizes; (void)n_in; (void)out_size;
    const float* rubin = (const float*)d_in[0];
    const float* vis   = (const float*)d_in[1];
    const float* p2s   = (const float*)d_in[2];
    const float* rW0   = (const float*)d_in[3];
    const float* rWs   = (const float*)d_in[4];
    const float* rG    = (const float*)d_in[5];
    const float* rBt   = (const float*)d_in[6];
    const float* vW0   = (const float*)d_in[7];
    const float* vWs   = (const float*)d_in[8];
    const float* vG    = (const float*)d_in[9];
    const float* vBt   = (const float*)d_in[10];
    const float* projR = (const float*)d_in[11];
    const float* projV = (const float*)d_in[12];
    const float* logT  = (const float*)d_in[13];
    const float* W1    = (const float*)d_in[14];
    const float* b1    = (const float*)d_in[15];
    const float* W2    = (const float*)d_in[16];
    const float* b2    = (const float*)d_in[17];
    const float* W3    = (const float*)d_in[18];
    const float* b3    = (const float*)d_in[19];
    float* out = (float*)d_out;

    // ---- workspace layout: fixed (full-batch small arrays) + per-chunk big
    float* ws = (float*)d_ws;
    float* gauss  = ws;                          // 4096
    float* statp  = gauss + 4096;                // NB*16*8 = 32768
    float* coefS  = statp + 32768;               // NB*64
    float* coefRF = coefS + 16384;
    float* coefVF = coefRF + 16384;
    float* swp    = coefVF + 16384;              // NB*16
    float* rp     = swp + 4096;                  // NB*32
    float* vp     = rp + 8192;                   // NB*32
    float* lgbuf  = vp + 8192;                   // NB*49 = 12544
    const size_t fixedf = 4096 + 32768 + 3 * 16384 + 4096 + 8192 + 8192 + 12544;
    const size_t perb = 3ull * 32 * HW + HW;     // A,B,C channel-bufs + E = 397312 floats

    size_t wsf = ws_size / sizeof(float);
    int BC = 1;
    if (wsf > fixedf + perb) {
        size_t t = (wsf - fixedf) / perb;
        BC = t > (size_t)NB ? NB : (int)t;
    }

    float* A  = ws + fixedf;
    float* Bb = A + (size_t)BC * 32 * HW;
    float* Cb = Bb + (size_t)BC * 32 * HW;
    float* E  = Cb + (size_t)BC * 32 * HW;

    dim3 blk(256);
    gauss_kernel<<<1, 256, 0, stream>>>(gauss);

    for (int b0 = 0; b0 < NB; b0 += BC) {
        const int bc = (NB - b0) < BC ? (NB - b0) : BC;
        dim3 cg(16, bc);
        const int gnblk = (bc * 32 + 255) / 256;
        float* sp = statp + (size_t)b0 * 128;
        float* cS = coefS + (size_t)b0 * 64;
        float* cR = coefRF + (size_t)b0 * 64;
        float* cV = coefVF + (size_t)b0 * 64;
        float* sw = swp + (size_t)b0 * 16;

        // ---- rubin encoder: conv0 -> A, A->B, B->A, A->B (raw final in B)
        conv3x3_kernel<6, false><<<cg, blk, 0, stream>>>(rubin + (size_t)b0 * 6 * HW, (const float*)nullptr, rW0, A, sp);
        gn_finalize_kernel<<<gnblk, 256, 0, stream>>>(sp, rG + 0, rBt + 0, cS, bc * 32);
        conv3x3_kernel<32, true><<<cg, blk, 0, stream>>>(A, cS, rWs + 0 * 9216, Bb, sp);
        gn_finalize_kernel<<<gnblk, 256, 0, stream>>>(sp, rG + 32, rBt + 32, cS, bc * 32);
        conv3x3_kernel<32, true><<<cg, blk, 0, stream>>>(Bb, cS, rWs + 1 * 9216, A, sp);
        gn_finalize_kernel<<<gnblk, 256, 0, stream>>>(sp, rG + 64, rBt + 64, cS, bc * 32);
        conv3x3_kernel<32, true><<<cg, blk, 0, stream>>>(A, cS, rWs + 2 * 9216, Bb, sp);
        gn_finalize_kernel<<<gnblk, 256, 0, stream>>>(sp, rG + 96, rBt + 96, cR, bc * 32);
        pool_kernel<<<dim3(32, bc), blk, 0, stream>>>(Bb, cR, gauss, rp + (size_t)b0 * 32);
        proj_kernel<<<cg, blk, 0, stream>>>(Bb, cR, projR, A, E, sw, gauss);  // rubin_n -> A

        // ---- vis encoder: conv0 -> B, B->C, C->B, B->C (raw final in C)
        conv3x3_kernel<1, false><<<cg, blk, 0, stream>>>(vis + (size_t)b0 * HW, (const float*)nullptr, vW0, Bb, sp);
        gn_finalize_kernel<<<gnblk, 256, 0, stream>>>(sp, vG + 0, vBt + 0, cS, bc * 32);
        conv3x3_kernel<32, true><<<cg, blk, 0, stream>>>(Bb, cS, vWs + 0 * 9216, Cb, sp);
        gn_finalize_kernel<<<gnblk, 256, 0, stream>>>(sp, vG + 32, vBt + 32, cS, bc * 32);
        conv3x3_kernel<32, true><<<cg, blk, 0, stream>>>(Cb, cS, vWs + 1 * 9216, Bb, sp);
        gn_finalize_kernel<<<gnblk, 256, 0, stream>>>(sp, vG + 64, vBt + 64, cS, bc * 32);
        conv3x3_kernel<32, true><<<cg, blk, 0, stream>>>(Bb, cS, vWs + 2 * 9216, Cb, sp);
        gn_finalize_kernel<<<gnblk, 256, 0, stream>>>(sp, vG + 96, vBt + 96, cV, bc * 32);
        pool_kernel<<<dim3(32, bc), blk, 0, stream>>>(Cb, cV, gauss, vp + (size_t)b0 * 32);
        proj_kernel<<<cg, blk, 0, stream>>>(Cb, cV, projV, Bb, (float*)nullptr, (float*)nullptr, gauss);  // vis_n -> B

        swapply_kernel<<<cg, blk, 0, stream>>>(E, sw, gauss);
        logits_kernel<<<bc, 256, 0, stream>>>(A, Bb, E, lgbuf + (size_t)b0 * 49);
    }

    head_kernel<<<NB, 128, 0, stream>>>(lgbuf, rp, vp, p2s, logT, W1, b1, W2, b2, W3, b3, out);
}

// Round 4
// 2791.947 us; speedup vs baseline: 2.1936x; 2.1936x over previous
//
#include <hip/hip_runtime.h>
#include <math.h>

#define HW 4096
#define NB 256

typedef __attribute__((ext_vector_type(8))) short bf16x8_t;
typedef __attribute__((ext_vector_type(16))) float f32x16_t;

__device__ __forceinline__ float gelu_f(float x) {
    return 0.5f * x * (1.0f + erff(x * 0.70710678118654752440f));
}
__device__ __forceinline__ unsigned short f2bf(float f) {
    unsigned int u = __float_as_uint(f);
    unsigned int r = u + 0x7FFFu + ((u >> 16) & 1u);
    return (unsigned short)(r >> 16);
}
__device__ __forceinline__ float bf2f(unsigned short h) {
    return __uint_as_float(((unsigned int)h) << 16);
}

// ---------------------------------------------------------------------------
// Gaussian center window
// ---------------------------------------------------------------------------
__global__ __launch_bounds__(256) void gauss_kernel(float* __restrict__ gauss) {
    __shared__ float sg[HW];
    __shared__ float sR[4];
    int tid = threadIdx.x;
    float part = 0.0f;
    for (int p = tid; p < HW; p += 256) {
        int y = p >> 6, x = p & 63;
        float yy = -1.0f + (2.0f / 63.0f) * (float)y;
        float xx = -1.0f + (2.0f / 63.0f) * (float)x;
        float g = expf(-(yy * yy + xx * xx) * 2.0f);
        sg[p] = g;
        part += g;
    }
#pragma unroll
    for (int off = 32; off > 0; off >>= 1) part += __shfl_down(part, off);
    if ((tid & 63) == 0) sR[tid >> 6] = part;
    __syncthreads();
    float invt = 1.0f / (sR[0] + sR[1] + sR[2] + sR[3]);
    for (int p = tid; p < HW; p += 256) gauss[p] = sg[p] * invt;
}

// ---------------------------------------------------------------------------
// Pack conv weights (fp32 OIHW) into MFMA B-fragment order, split bf16 hi/lo.
// wq[frag][lane][j], frag = ((layer*9+tap)*2 + kstep)*2 + hl, 512 shorts/frag.
// Lane: co = lane&31, half = lane>>5; ci = kstep*16 + half*8 + j.
// Layers 0-2 = rubin rWs, 3-5 = vis vWs.  Total 110592 shorts.
// ---------------------------------------------------------------------------
__global__ __launch_bounds__(256) void prep_w_kernel(
    const float* __restrict__ rWs, const float* __restrict__ vWs,
    unsigned short* __restrict__ wq) {
    int i = blockIdx.x * 256 + threadIdx.x;
    if (i >= 110592) return;
    int j = i & 7;
    int lane = (i >> 3) & 63;
    int f = i >> 9;
    int hl = f & 1, k2 = (f >> 1) & 1, tap = (f >> 2) % 9, layer = (f >> 2) / 9;
    int co = lane & 31, hf = lane >> 5;
    int ci = k2 * 16 + hf * 8 + j;
    int ky = tap / 3, kx = tap % 3;
    float wv = (layer < 3)
        ? rWs[(((size_t)layer * 32 + co) * 32 + ci) * 9 + ky * 3 + kx]
        : vWs[(((size_t)(layer - 3) * 32 + co) * 32 + ci) * 9 + ky * 3 + kx];
    unsigned short h = f2bf(wv);
    unsigned short l = f2bf(wv - bf2f(h));
    wq[i] = hl ? l : h;
}

// ---------------------------------------------------------------------------
// First conv layer (CIN=6 rubin / CIN=1 vis), fp32 VALU. Reads NCHW input,
// writes RAW conv output in swizzled split-bf16 pixel-block Q format:
// per pixel 128B: 8 sub-blocks of 16B (h0-3 = ci groups of 8, l0-3),
// sub-block s stored at ((s + (x&7)) & 7)*16.  Also per-strip GN stats.
// ---------------------------------------------------------------------------
template <int CIN>
__global__ __launch_bounds__(256) void conv_first_kernel(
    const float* __restrict__ in, const float* __restrict__ w,
    unsigned short* __restrict__ qout, float* __restrict__ statp) {
    const int b = blockIdx.y;
    const int strip = blockIdx.x;
    const int tid = threadIdx.x;
    const int x = tid & 63;
    const int wid = tid >> 6;

    __shared__ float sIn[CIN][6][66];
    __shared__ float sRed[4][8];

    const float* inb = in + (size_t)b * CIN * HW;
    for (int idx = tid; idx < CIN * 6 * 66; idx += 256) {
        int ci = idx / (6 * 66);
        int rem = idx - ci * (6 * 66);
        int r = rem / 66;
        int p = rem - r * 66;
        int gy = strip * 4 - 1 + r;
        int gx = p - 1;
        float v = 0.0f;
        if (gy >= 0 && gy < 64 && gx >= 0 && gx < 64) v = inb[ci * HW + gy * 64 + gx];
        sIn[ci][r][p] = v;
    }
    __syncthreads();

    float acc[32];
#pragma unroll
    for (int co = 0; co < 32; ++co) acc[co] = 0.0f;

    for (int ci = 0; ci < CIN; ++ci) {
        float vv[9];
#pragma unroll
        for (int ky = 0; ky < 3; ++ky)
#pragma unroll
            for (int kx = 0; kx < 3; ++kx) vv[ky * 3 + kx] = sIn[ci][wid + ky][x + kx];
#pragma unroll
        for (int co = 0; co < 32; ++co) {
            const float* wk = w + ((size_t)co * CIN + ci) * 9;
            float s = acc[co];
#pragma unroll
            for (int k = 0; k < 9; ++k) s = fmaf(wk[k], vv[k], s);
            acc[co] = s;
        }
    }

    const int gy = strip * 4 + wid;
    // store Q format
    {
        int rot = x & 7;
        char* pb = (char*)qout + (((size_t)b * HW) + (size_t)gy * 64 + x) * 128;
#pragma unroll
        for (int s = 0; s < 4; ++s) {
            unsigned int hw_[4], lw_[4];
#pragma unroll
            for (int e = 0; e < 4; ++e) {
                int c = s * 8 + e * 2;
                unsigned short h0 = f2bf(acc[c]);
                float r0 = acc[c] - bf2f(h0);
                unsigned short h1 = f2bf(acc[c + 1]);
                float r1 = acc[c + 1] - bf2f(h1);
                hw_[e] = (unsigned)h0 | ((unsigned)h1 << 16);
                lw_[e] = (unsigned)f2bf(r0) | ((unsigned)f2bf(r1) << 16);
            }
            uint4 uh; uh.x = hw_[0]; uh.y = hw_[1]; uh.z = hw_[2]; uh.w = hw_[3];
            uint4 ul; ul.x = lw_[0]; ul.y = lw_[1]; ul.z = lw_[2]; ul.w = lw_[3];
            *(uint4*)(pb + (((s + rot) & 7) * 16)) = uh;
            *(uint4*)(pb + (((s + 4 + rot) & 7) * 16)) = ul;
        }
    }
    // stats
    float s1[4] = {0, 0, 0, 0}, s2[4] = {0, 0, 0, 0};
#pragma unroll
    for (int co = 0; co < 32; ++co) {
        float v = acc[co];
        s1[co >> 3] += v;
        s2[co >> 3] = fmaf(v, v, s2[co >> 3]);
    }
#pragma unroll
    for (int off = 32; off > 0; off >>= 1) {
#pragma unroll
        for (int g = 0; g < 4; ++g) {
            s1[g] += __shfl_down(s1[g], off);
            s2[g] += __shfl_down(s2[g], off);
        }
    }
    if ((tid & 63) == 0) {
#pragma unroll
        for (int g = 0; g < 4; ++g) {
            sRed[wid][g] = s1[g];
            sRed[wid][4 + g] = s2[g];
        }
    }
    __syncthreads();
    if (tid < 8) {
        float t = sRed[0][tid] + sRed[1][tid] + sRed[2][tid] + sRed[3][tid];
        statp[((size_t)b * 16 + strip) * 8 + tid] = t;
    }
}

// ---------------------------------------------------------------------------
// GN finalize: per-strip stats -> per-(b,c) affine coefs  y = a*x + b
// ---------------------------------------------------------------------------
__global__ __launch_bounds__(256) void gn_finalize_kernel(
    const float* __restrict__ statp, const float* __restrict__ gma,
    const float* __restrict__ bta, float* __restrict__ coef, int n) {
    int i = blockIdx.x * 256 + threadIdx.x;
    if (i >= n) return;
    int b = i >> 5, c = i & 31, g = c >> 3;
    float s1 = 0.0f, s2 = 0.0f;
    for (int s = 0; s < 16; ++s) {
        s1 += statp[((size_t)b * 16 + s) * 8 + g];
        s2 += statp[((size_t)b * 16 + s) * 8 + 4 + g];
    }
    const float invN = 1.0f / 32768.0f;
    float mean = s1 * invN;
    float var = s2 * invN - mean * mean;
    float rstd = rsqrtf(var + 1e-5f);
    float a = rstd * gma[c];
    float bb = bta[c] - mean * a;
    coef[i * 2 + 0] = a;
    coef[i * 2 + 1] = bb;
}

// ---------------------------------------------------------------------------
// In-place activation on Q: x = h+l; y = gelu(a*x+b); re-split to (h,l).
// Grid (16 px-chunks, bc), thread per pixel.
// ---------------------------------------------------------------------------
__global__ __launch_bounds__(256) void act_kernel(
    unsigned short* __restrict__ q, const float* __restrict__ coef) {
    int b = blockIdx.y, t = threadIdx.x;
    int p = blockIdx.x * 256 + t;
    __shared__ float sc[64];
    if (t < 64) sc[t] = coef[b * 64 + t];
    __syncthreads();
    int rot = p & 7;
    char* pb = (char*)q + (((size_t)b * HW) + p) * 128;
    uint4 uh[4], ul[4];
#pragma unroll
    for (int s = 0; s < 4; ++s) uh[s] = *(const uint4*)(pb + (((s + rot) & 7) * 16));
#pragma unroll
    for (int s = 0; s < 4; ++s) ul[s] = *(const uint4*)(pb + (((s + 4 + rot) & 7) * 16));
#pragma unroll
    for (int s = 0; s < 4; ++s) {
        unsigned int hd[4] = {uh[s].x, uh[s].y, uh[s].z, uh[s].w};
        unsigned int ld[4] = {ul[s].x, ul[s].y, ul[s].z, ul[s].w};
        unsigned int ho[4], lo_[4];
#pragma unroll
        for (int e = 0; e < 4; ++e) {
            int c0 = s * 8 + e * 2;
            float x0 = bf2f((unsigned short)(hd[e] & 0xFFFF)) + bf2f((unsigned short)(ld[e] & 0xFFFF));
            float x1 = bf2f((unsigned short)(hd[e] >> 16)) + bf2f((unsigned short)(ld[e] >> 16));
            float y0 = gelu_f(fmaf(sc[c0 * 2], x0, sc[c0 * 2 + 1]));
            float y1 = gelu_f(fmaf(sc[(c0 + 1) * 2], x1, sc[(c0 + 1) * 2 + 1]));
            unsigned short h0 = f2bf(y0), h1 = f2bf(y1);
            unsigned short l0 = f2bf(y0 - bf2f(h0)), l1 = f2bf(y1 - bf2f(h1));
            ho[e] = (unsigned)h0 | ((unsigned)h1 << 16);
            lo_[e] = (unsigned)l0 | ((unsigned)l1 << 16);
        }
        uint4 oh; oh.x = ho[0]; oh.y = ho[1]; oh.z = ho[2]; oh.w = ho[3];
        uint4 ol; ol.x = lo_[0]; ol.y = lo_[1]; ol.z = lo_[2]; ol.w = lo_[3];
        *(uint4*)(pb + (((s + rot) & 7) * 16)) = oh;
        *(uint4*)(pb + (((s + 4 + rot) & 7) * 16)) = ol;
    }
}

// ---------------------------------------------------------------------------
// MFMA 3x3 conv, CIN=COUT=32, split-bf16 3-term (xh*wh + xh*wl + xl*wh).
// Block = 128 thr = 2 waves (x-halves), strip of 4 output rows; grid (16, bc).
// LDS: 6 staged input rows x 66 slots x 128B (swizzled pixel-blocks).
// Wave = 4 rows x 32 px: 4 C-frags of v_mfma_f32_32x32x16_bf16.
// Writes raw Q (split-bf16) + per-strip GN stats.
// ---------------------------------------------------------------------------
__global__ __launch_bounds__(128) void convm_kernel(
    const unsigned short* __restrict__ qin, const unsigned short* __restrict__ wq,
    unsigned short* __restrict__ qout, float* __restrict__ statp) {
    const int b = blockIdx.y;
    const int strip = blockIdx.x;
    const int tid = threadIdx.x;
    const int wv = tid >> 6;
    const int lane = tid & 63;
    const int m = lane & 31;
    const int hf = lane >> 5;
    const int xh32 = wv * 32;

    __shared__ __align__(16) char sQ[6 * 8448];
    __shared__ float sRed[2][8];

    const int y0 = strip * 4;
    const char* img = (const char*)qin + (size_t)b * HW * 128;
#pragma unroll 6
    for (int k = 0; k < 24; ++k) {
        int c = k * 2 + wv;
        int r = c >> 3;
        int within = (c & 7) * 1024;
        int gy = y0 - 1 + r;
        char* dst = sQ + r * 8448 + 128 + within + lane * 16;
        if (gy >= 0 && gy < 64) {
            *(uint4*)dst = *(const uint4*)(img + (size_t)gy * 8192 + within + lane * 16);
        } else {
            uint4 z; z.x = z.y = z.z = z.w = 0;
            *(uint4*)dst = z;
        }
    }
    if (tid < 96) {
        int pb_ = tid >> 3, sub = tid & 7;
        int r = pb_ >> 1, side = pb_ & 1;
        uint4 z; z.x = z.y = z.z = z.w = 0;
        *(uint4*)(sQ + r * 8448 + side * 8320 + sub * 16) = z;
    }
    __syncthreads();

    f32x16_t acc[4];
#pragma unroll
    for (int i = 0; i < 4; ++i)
#pragma unroll
        for (int j = 0; j < 16; ++j) acc[i][j] = 0.0f;

    for (int kx = 0; kx < 3; ++kx) {
        bf16x8_t Wf[3][2][2];  // [ky][kstep][hl]
#pragma unroll
        for (int ky = 0; ky < 3; ++ky)
#pragma unroll
            for (int k2 = 0; k2 < 2; ++k2)
#pragma unroll
                for (int hl = 0; hl < 2; ++hl) {
                    int fi = ((ky * 3 + kx) * 2 + k2) * 2 + hl;
                    Wf[ky][k2][hl] = __builtin_bit_cast(
                        bf16x8_t, *(const uint4*)(wq + (size_t)fi * 512 + lane * 8));
                }
        const int slotb = xh32 + kx + m;
        const int rot = (m + kx + 7) & 7;
#pragma unroll
        for (int li = 0; li < 6; ++li) {
            const char* rowp = sQ + li * 8448 + slotb * 128;
            bf16x8_t Ah[2], Al[2];
#pragma unroll
            for (int k2 = 0; k2 < 2; ++k2) {
                int sh = k2 * 2 + hf;
                Ah[k2] = __builtin_bit_cast(bf16x8_t, *(const uint4*)(rowp + ((sh + rot) & 7) * 16));
                Al[k2] = __builtin_bit_cast(bf16x8_t, *(const uint4*)(rowp + ((sh + 4 + rot) & 7) * 16));
            }
#pragma unroll
            for (int ky = 0; ky < 3; ++ky) {
                int orow = li - ky;
                if (orow < 0 || orow > 3) continue;
#pragma unroll
                for (int k2 = 0; k2 < 2; ++k2) {
                    acc[orow] = __builtin_amdgcn_mfma_f32_32x32x16_bf16(Ah[k2], Wf[ky][k2][0], acc[orow], 0, 0, 0);
                    acc[orow] = __builtin_amdgcn_mfma_f32_32x32x16_bf16(Ah[k2], Wf[ky][k2][1], acc[orow], 0, 0, 0);
                    acc[orow] = __builtin_amdgcn_mfma_f32_32x32x16_bf16(Al[k2], Wf[ky][k2][0], acc[orow], 0, 0, 0);
                }
            }
        }
    }

    // store raw Q + collect stats
    const int co = lane & 31;
    char* ob = (char*)qout + (size_t)b * HW * 128;
    float s1 = 0.0f, s2 = 0.0f;
#pragma unroll
    for (int orow = 0; orow < 4; ++orow) {
        int y = y0 + orow;
#pragma unroll
        for (int r = 0; r < 16; ++r) {
            int mm = (r & 3) + 8 * (r >> 2) + 4 * hf;
            int x = xh32 + mm;
            float v = acc[orow][r];
            s1 += v;
            s2 = fmaf(v, v, s2);
            unsigned short hv = f2bf(v);
            unsigned short lv = f2bf(v - bf2f(hv));
            int rot2 = mm & 7;
            char* pb = ob + ((size_t)y * 64 + x) * 128;
            *(unsigned short*)(pb + (((co >> 3) + rot2) & 7) * 16 + (co & 7) * 2) = hv;
            *(unsigned short*)(pb + (((co >> 3) + 4 + rot2) & 7) * 16 + (co & 7) * 2) = lv;
        }
    }
    s1 += __shfl_xor(s1, 32); s2 += __shfl_xor(s2, 32);
    s1 += __shfl_xor(s1, 1);  s2 += __shfl_xor(s2, 1);
    s1 += __shfl_xor(s1, 2);  s2 += __shfl_xor(s2, 2);
    s1 += __shfl_xor(s1, 4);  s2 += __shfl_xor(s2, 4);
    if (lane < 32 && (lane & 7) == 0) {
        sRed[wv][co >> 3] = s1;
        sRed[wv][4 + (co >> 3)] = s2;
    }
    __syncthreads();
    if (tid < 8) statp[((size_t)b * 16 + strip) * 8 + tid] = sRed[0][tid] + sRed[1][tid];
}

// ---------------------------------------------------------------------------
// Gauss-pool of ACTIVATED Q: outp[b,c] = sum_p feat(p,c)*gauss(p). Block per b.
// ---------------------------------------------------------------------------
__global__ __launch_bounds__(256) void pool_kernel(
    const unsigned short* __restrict__ q, const float* __restrict__ gauss,
    float* __restrict__ outp) {
    int b = blockIdx.x, t = threadIdx.x;
    __shared__ float red[32][257];
    float acc[32];
#pragma unroll
    for (int c = 0; c < 32; ++c) acc[c] = 0.0f;
    for (int p = t; p < HW; p += 256) {
        float g = gauss[p];
        int rot = p & 7;
        const char* pb = (const char*)q + (((size_t)b * HW) + p) * 128;
#pragma unroll
        for (int s = 0; s < 4; ++s) {
            uint4 uh = *(const uint4*)(pb + (((s + rot) & 7) * 16));
            uint4 ul = *(const uint4*)(pb + (((s + 4 + rot) & 7) * 16));
            unsigned int hd[4] = {uh.x, uh.y, uh.z, uh.w};
            unsigned int ld[4] = {ul.x, ul.y, ul.z, ul.w};
#pragma unroll
            for (int e = 0; e < 4; ++e) {
                int c0 = s * 8 + e * 2;
                float x0 = bf2f((unsigned short)(hd[e] & 0xFFFF)) + bf2f((unsigned short)(ld[e] & 0xFFFF));
                float x1 = bf2f((unsigned short)(hd[e] >> 16)) + bf2f((unsigned short)(ld[e] >> 16));
                acc[c0] = fmaf(x0, g, acc[c0]);
                acc[c0 + 1] = fmaf(x1, g, acc[c0 + 1]);
            }
        }
    }
#pragma unroll
    for (int c = 0; c < 32; ++c) red[c][t] = acc[c];
    __syncthreads();
    if (t < 32) {
        float s = 0.0f;
        for (int i = 0; i < 256; ++i) s += red[t][i];
        outp[b * 32 + t] = s;
    }
}

// ---------------------------------------------------------------------------
// Projection + l2norm from ACTIVATED Q. Writes bf16 NCHW planes (+E, swp).
// ---------------------------------------------------------------------------
__global__ __launch_bounds__(256) void proj_kernel(
    const unsigned short* __restrict__ q, const float* __restrict__ pw,
    unsigned short* __restrict__ outn, float* __restrict__ E,
    float* __restrict__ swp, const float* __restrict__ gauss) {
    int b = blockIdx.y, chunk = blockIdx.x, tid = threadIdx.x;
    int p = chunk * 256 + tid;
    __shared__ float sR[4];
    float feat[32];
    {
        int rot = p & 7;
        const char* pb = (const char*)q + (((size_t)b * HW) + p) * 128;
#pragma unroll
        for (int s = 0; s < 4; ++s) {
            uint4 uh = *(const uint4*)(pb + (((s + rot) & 7) * 16));
            uint4 ul = *(const uint4*)(pb + (((s + 4 + rot) & 7) * 16));
            unsigned int hd[4] = {uh.x, uh.y, uh.z, uh.w};
            unsigned int ld[4] = {ul.x, ul.y, ul.z, ul.w};
#pragma unroll
            for (int e = 0; e < 4; ++e) {
                int c0 = s * 8 + e * 2;
                feat[c0] = bf2f((unsigned short)(hd[e] & 0xFFFF)) + bf2f((unsigned short)(ld[e] & 0xFFFF));
                feat[c0 + 1] = bf2f((unsigned short)(hd[e] >> 16)) + bf2f((unsigned short)(ld[e] >> 16));
            }
        }
    }
    float o[32];
#pragma unroll
    for (int oo = 0; oo < 32; ++oo) o[oo] = 0.0f;
    for (int c = 0; c < 32; ++c) {
        float f = feat[c];
#pragma unroll
        for (int oo = 0; oo < 32; ++oo) o[oo] = fmaf(pw[oo * 32 + c], f, o[oo]);
    }
    float nn = 0.0f;
#pragma unroll
    for (int oo = 0; oo < 32; ++oo) nn = fmaf(o[oo], o[oo], nn);
    float n = sqrtf(nn);
    float inv = 1.0f / fmaxf(n, 1e-6f);
    unsigned short* obp = outn + (size_t)b * 32 * HW + p;
#pragma unroll
    for (int oo = 0; oo < 32; ++oo) obp[(size_t)oo * HW] = f2bf(o[oo] * inv);
    if (E != nullptr) {
        float e = nn * inv * inv;
        E[(size_t)b * HW + p] = e;
        float wvv = e * gauss[p];
#pragma unroll
        for (int off = 32; off > 0; off >>= 1) wvv += __shfl_down(wvv, off);
        if ((tid & 63) == 0) sR[tid >> 6] = wvv;
        __syncthreads();
        if (tid == 0) swp[b * 16 + chunk] = sR[0] + sR[1] + sR[2] + sR[3];
    }
}

// ---------------------------------------------------------------------------
// E <- E * gauss * scale / (sum_p(E*gauss) + 1e-8)
// ---------------------------------------------------------------------------
__global__ __launch_bounds__(256) void swapply_kernel(
    float* __restrict__ E, const float* __restrict__ swp,
    const float* __restrict__ gauss) {
    int b = blockIdx.y, p = blockIdx.x * 256 + threadIdx.x;
    float s = 0.0f;
#pragma unroll
    for (int i = 0; i < 16; ++i) s += swp[b * 16 + i];
    const float scale = 0.17677669529663688f;
    E[(size_t)b * HW + p] = E[(size_t)b * HW + p] * gauss[p] * scale / (s + 1e-8f);
}

// ---------------------------------------------------------------------------
// 49-offset correlation logits on bf16 rn/vn planes.
// ---------------------------------------------------------------------------
__global__ __launch_bounds__(256) void logits_kernel(
    const unsigned short* __restrict__ rn, const unsigned short* __restrict__ vn,
    const float* __restrict__ sw, float* __restrict__ logits) {
    int b = blockIdx.x, tid = threadIdx.x;
    __shared__ float P[38][76];
    __shared__ float sR[4][49];
    float acc[49];
#pragma unroll
    for (int k = 0; k < 49; ++k) acc[k] = 0.0f;
    const float* swb = sw + (size_t)b * HW;
    for (int c = 0; c < 32; ++c) {
        const unsigned short* vb = vn + ((size_t)b * 32 + c) * HW;
        const unsigned short* rb = rn + ((size_t)b * 32 + c) * HW;
#pragma unroll 1
        for (int half = 0; half < 2; ++half) {
            const int base = half * 32;
            __syncthreads();
            for (int idx = tid; idx < 38 * 72; idx += 256) {
                int r = idx / 72, j = idx - r * 72;
                int gy = base - 3 + r;
                gy = gy < 0 ? 0 : (gy > 63 ? 63 : gy);
                int gx = j - 4;
                gx = gx < 0 ? 0 : (gx > 63 ? 63 : gx);
                P[r][j] = bf2f(vb[gy * 64 + gx]);
            }
            __syncthreads();
            int y = tid >> 3, x0 = (tid & 7) * 8;
            int pbase = (base + y) * 64 + x0;
            uint4 rv = *(const uint4*)(rb + pbase);
            float4 q0 = *(const float4*)(swb + pbase);
            float4 q1 = *(const float4*)(swb + pbase + 4);
            unsigned int rd[4] = {rv.x, rv.y, rv.z, rv.w};
            float r_[8];
            r_[0] = bf2f((unsigned short)(rd[0] & 0xFFFF)) * q0.x;
            r_[1] = bf2f((unsigned short)(rd[0] >> 16)) * q0.y;
            r_[2] = bf2f((unsigned short)(rd[1] & 0xFFFF)) * q0.z;
            r_[3] = bf2f((unsigned short)(rd[1] >> 16)) * q0.w;
            r_[4] = bf2f((unsigned short)(rd[2] & 0xFFFF)) * q1.x;
            r_[5] = bf2f((unsigned short)(rd[2] >> 16)) * q1.y;
            r_[6] = bf2f((unsigned short)(rd[3] & 0xFFFF)) * q1.z;
            r_[7] = bf2f((unsigned short)(rd[3] >> 16)) * q1.w;
#pragma unroll
            for (int dy = 0; dy < 7; ++dy) {
                const float4* Pr = (const float4*)(&P[y + dy][x0]);
                float4 a0 = Pr[0], a1 = Pr[1], a2 = Pr[2], a3 = Pr[3];
                float v[16] = {a0.x, a0.y, a0.z, a0.w, a1.x, a1.y, a1.z, a1.w,
                               a2.x, a2.y, a2.z, a2.w, a3.x, a3.y, a3.z, a3.w};
#pragma unroll
                for (int dx = 0; dx < 7; ++dx) {
#pragma unroll
                    for (int j = 0; j < 8; ++j)
                        acc[dy * 7 + dx] = fmaf(r_[j], v[j + dx + 1], acc[dy * 7 + dx]);
                }
            }
        }
    }
#pragma unroll
    for (int k = 0; k < 49; ++k) {
#pragma unroll
        for (int off = 32; off > 0; off >>= 1) acc[k] += __shfl_down(acc[k], off);
    }
    int wid = tid >> 6;
    __syncthreads();
    if ((tid & 63) == 0) {
#pragma unroll
        for (int k = 0; k < 49; ++k) sR[wid][k] = acc[k];
    }
    __syncthreads();
    if (tid < 49)
        logits[b * 49 + tid] = sR[0][tid] + sR[1][tid] + sR[2][tid] + sR[3][tid];
}

// ---------------------------------------------------------------------------
// Softmax/coarse + MLP head + output assembly.
// ---------------------------------------------------------------------------
__global__ __launch_bounds__(128) void head_kernel(
    const float* __restrict__ lg, const float* __restrict__ rp,
    const float* __restrict__ vp, const float* __restrict__ p2s,
    const float* __restrict__ log_temp,
    const float* __restrict__ W1, const float* __restrict__ b1,
    const float* __restrict__ W2, const float* __restrict__ b2,
    const float* __restrict__ W3, const float* __restrict__ b3,
    float* __restrict__ out) {
    int b = blockIdx.x, t = threadIdx.x;
    __shared__ float pooled[98];
    __shared__ float h1[128], h2[128];
    __shared__ float cxy[2];
    __shared__ float res[3];
    const float* lgb = lg + b * 49;
    if (t == 0) {
        float temp = fmaxf(expf(log_temp[0]), 0.001f);
        float invT = 1.0f / temp;
        float m = -1e30f;
        for (int k = 0; k < 49; ++k) m = fmaxf(m, lgb[k] * invT);
        float s = 0.0f, pdx = 0.0f, pdy = 0.0f;
        for (int k = 0; k < 49; ++k) {
            float e = expf(lgb[k] * invT - m);
            s += e;
            pdx += e * (float)((k % 7) - 3);
            pdy += e * (float)((k / 7) - 3);
        }
        cxy[0] = pdx / s;
        cxy[1] = pdy / s;
    }
    __syncthreads();
    if (t < 32) {
        float a = rp[b * 32 + t], c = vp[b * 32 + t];
        pooled[t] = a;
        pooled[32 + t] = c;
        pooled[64 + t] = a - c;
    }
    if (t == 0) {
        pooled[96] = cxy[0];
        pooled[97] = cxy[1];
    }
    __syncthreads();
    float s1 = b1[t];
    for (int i = 0; i < 98; ++i) s1 = fmaf(pooled[i], W1[i * 128 + t], s1);
    h1[t] = gelu_f(s1);
    __syncthreads();
    float s2 = b2[t];
    for (int i = 0; i < 128; ++i) s2 = fmaf(h1[i], W2[i * 128 + t], s2);
    h2[t] = gelu_f(s2);
    __syncthreads();
    if (t < 3) {
        float r = b3[t];
        for (int i = 0; i < 128; ++i) r = fmaf(h2[i], W3[i * 3 + t], r);
        res[t] = r;
    }
    __syncthreads();
    if (t == 0) {
        float dxp = cxy[0] + res[0];
        float dyp = cxy[1] + res[1];
        float ls = fminf(fmaxf(res[2], -6.0f), 3.0f);
        const float* M = p2s + b * 4;
        float* ob = out + b * 54;
        ob[0] = dxp;
        ob[1] = dyp;
        ob[2] = M[0] * dxp + M[1] * dyp;
        ob[3] = M[2] * dxp + M[3] * dyp;
        ob[4] = ls;
    }
    if (t < 49) out[b * 54 + 5 + t] = lgb[t];
}

extern "C" void kernel_launch(void* const* d_in, const int* in_sizes, int n_in,
                              void* d_out, int out_size, void* d_ws, size_t ws_size,
                              hipStream_t stream) {
    (void)in_sizes; (void)n_in; (void)out_size;
    const float* rubin = (const float*)d_in[0];
    const float* vis   = (const float*)d_in[1];
    const float* p2s   = (const float*)d_in[2];
    const float* rW0   = (const float*)d_in[3];
    const float* rWs   = (const float*)d_in[4];
    const float* rG    = (const float*)d_in[5];
    const float* rBt   = (const float*)d_in[6];
    const float* vW0   = (const float*)d_in[7];
    const float* vWs   = (const float*)d_in[8];
    const float* vG    = (const float*)d_in[9];
    const float* vBt   = (const float*)d_in[10];
    const float* projR = (const float*)d_in[11];
    const float* projV = (const float*)d_in[12];
    const float* logT  = (const float*)d_in[13];
    const float* W1    = (const float*)d_in[14];
    const float* b1    = (const float*)d_in[15];
    const float* W2    = (const float*)d_in[16];
    const float* b2    = (const float*)d_in[17];
    const float* W3    = (const float*)d_in[18];
    const float* b3    = (const float*)d_in[19];
    float* out = (float*)d_out;

    // ---- workspace layout (bytes)
    char* ws = (char*)d_ws;
    size_t off = 0;
    unsigned short* vnB = (unsigned short*)(ws + off); off += (size_t)NB * 32 * HW * 2;  // 67.1 MB
    float* gauss  = (float*)(ws + off); off += HW * 4;
    float* statp  = (float*)(ws + off); off += (size_t)NB * 16 * 8 * 4;
    float* coefS  = (float*)(ws + off); off += (size_t)NB * 64 * 4;
    float* swp    = (float*)(ws + off); off += (size_t)NB * 16 * 4;
    float* rp     = (float*)(ws + off); off += (size_t)NB * 32 * 4;
    float* vp     = (float*)(ws + off); off += (size_t)NB * 32 * 4;
    float* lgbuf  = (float*)(ws + off); off += (size_t)NB * 49 * 4;
    unsigned short* wq = (unsigned short*)(ws + off); off += 110592ull * 2;
    off = (off + 255) & ~(size_t)255;
    const size_t fixed_bytes = off;
    const size_t perb = 2ull * HW * 128 + HW * 4;  // Q1+Q2 pixel blocks + E
    int BC = 1;
    if (ws_size > fixed_bytes + perb) {
        size_t t = (ws_size - fixed_bytes) / perb;
        BC = t > (size_t)NB ? NB : (int)t;
    }
    unsigned short* Q1 = (unsigned short*)(ws + off);
    unsigned short* Q2 = (unsigned short*)(ws + off + (size_t)BC * HW * 128);
    float* E = (float*)(ws + off + 2ull * BC * HW * 128);

    dim3 blk256(256), blk128(128);
    gauss_kernel<<<1, 256, 0, stream>>>(gauss);
    prep_w_kernel<<<432, 256, 0, stream>>>(rWs, vWs, wq);

    // ================= VIS encoder (all chunks) =================
    for (int b0 = 0; b0 < NB; b0 += BC) {
        const int bc = (NB - b0) < BC ? (NB - b0) : BC;
        dim3 cg16(16, bc);
        const int gnblk = (bc * 32 + 255) / 256;
        float* sp = statp + (size_t)b0 * 128;
        float* cS = coefS + (size_t)b0 * 64;

        conv_first_kernel<1><<<cg16, blk256, 0, stream>>>(vis + (size_t)b0 * HW, vW0, Q1, sp);
        gn_finalize_kernel<<<gnblk, 256, 0, stream>>>(sp, vG + 0, vBt + 0, cS, bc * 32);
        act_kernel<<<cg16, blk256, 0, stream>>>(Q1, cS);
        convm_kernel<<<cg16, blk128, 0, stream>>>(Q1, wq + 3 * 18432, Q2, sp);
        gn_finalize_kernel<<<gnblk, 256, 0, stream>>>(sp, vG + 32, vBt + 32, cS, bc * 32);
        act_kernel<<<cg16, blk256, 0, stream>>>(Q2, cS);
        convm_kernel<<<cg16, blk128, 0, stream>>>(Q2, wq + 4 * 18432, Q1, sp);
        gn_finalize_kernel<<<gnblk, 256, 0, stream>>>(sp, vG + 64, vBt + 64, cS, bc * 32);
        act_kernel<<<cg16, blk256, 0, stream>>>(Q1, cS);
        convm_kernel<<<cg16, blk128, 0, stream>>>(Q1, wq + 5 * 18432, Q2, sp);
        gn_finalize_kernel<<<gnblk, 256, 0, stream>>>(sp, vG + 96, vBt + 96, cS, bc * 32);
        act_kernel<<<cg16, blk256, 0, stream>>>(Q2, cS);
        pool_kernel<<<bc, blk256, 0, stream>>>(Q2, gauss, vp + (size_t)b0 * 32);
        proj_kernel<<<cg16, blk256, 0, stream>>>(Q2, projV, vnB + (size_t)b0 * 32 * HW,
                                                 (float*)nullptr, (float*)nullptr, gauss);
    }

    // ================= RUBIN encoder + logits (all chunks) =================
    for (int b0 = 0; b0 < NB; b0 += BC) {
        const int bc = (NB - b0) < BC ? (NB - b0) : BC;
        dim3 cg16(16, bc);
        const int gnblk = (bc * 32 + 255) / 256;
        float* sp = statp + (size_t)b0 * 128;
        float* cS = coefS + (size_t)b0 * 64;
        float* sw = swp + (size_t)b0 * 16;
        unsigned short* rnB = Q1;  // dead after last convm reads it

        conv_first_kernel<6><<<cg16, blk256, 0, stream>>>(rubin + (size_t)b0 * 6 * HW, rW0, Q1, sp);
        gn_finalize_kernel<<<gnblk, 256, 0, stream>>>(sp, rG + 0, rBt + 0, cS, bc * 32);
        act_kernel<<<cg16, blk256, 0, stream>>>(Q1, cS);
        convm_kernel<<<cg16, blk128, 0, stream>>>(Q1, wq + 0 * 18432, Q2, sp);
        gn_finalize_kernel<<<gnblk, 256, 0, stream>>>(sp, rG + 32, rBt + 32, cS, bc * 32);
        act_kernel<<<cg16, blk256, 0, stream>>>(Q2, cS);
        convm_kernel<<<cg16, blk128, 0, stream>>>(Q2, wq + 1 * 18432, Q1, sp);
        gn_finalize_kernel<<<gnblk, 256, 0, stream>>>(sp, rG + 64, rBt + 64, cS, bc * 32);
        act_kernel<<<cg16, blk256, 0, stream>>>(Q1, cS);
        convm_kernel<<<cg16, blk128, 0, stream>>>(Q1, wq + 2 * 18432, Q2, sp);
        gn_finalize_kernel<<<gnblk, 256, 0, stream>>>(sp, rG + 96, rBt + 96, cS, bc * 32);
        act_kernel<<<cg16, blk256, 0, stream>>>(Q2, cS);
        pool_kernel<<<bc, blk256, 0, stream>>>(Q2, gauss, rp + (size_t)b0 * 32);
        proj_kernel<<<cg16, blk256, 0, stream>>>(Q2, projR, rnB, E, sw, gauss);
        swapply_kernel<<<cg16, blk256, 0, stream>>>(E, sw, gauss);
        logits_kernel<<<bc, blk256, 0, stream>>>(rnB, vnB + (size_t)b0 * 32 * HW, E,
                                                 lgbuf + (size_t)b0 * 49);
    }

    head_kernel<<<NB, 128, 0, stream>>>(lgbuf, rp, vp, p2s, logT, W1, b1, W2, b2, W3, b3, out);
}

// Round 5
// 2242.675 us; speedup vs baseline: 2.7309x; 1.2449x over previous
//
#include <hip/hip_runtime.h>
#include <math.h>

#define HW 4096
#define NB 256

typedef __attribute__((ext_vector_type(8))) short bf16x8_t;
typedef __attribute__((ext_vector_type(16))) float f32x16_t;

__device__ __forceinline__ float gelu_f(float x) {
    return 0.5f * x * (1.0f + erff(x * 0.70710678118654752440f));
}
__device__ __forceinline__ unsigned short f2bf(float f) {
    unsigned int u = __float_as_uint(f);
    unsigned int r = u + 0x7FFFu + ((u >> 16) & 1u);
    return (unsigned short)(r >> 16);
}
__device__ __forceinline__ float bf2f(unsigned short h) {
    return __uint_as_float(((unsigned int)h) << 16);
}

// ---------------------------------------------------------------------------
// Gaussian center window
// ---------------------------------------------------------------------------
__global__ __launch_bounds__(256) void gauss_kernel(float* __restrict__ gauss) {
    __shared__ float sg[HW];
    __shared__ float sR[4];
    int tid = threadIdx.x;
    float part = 0.0f;
    for (int p = tid; p < HW; p += 256) {
        int y = p >> 6, x = p & 63;
        float yy = -1.0f + (2.0f / 63.0f) * (float)y;
        float xx = -1.0f + (2.0f / 63.0f) * (float)x;
        float g = expf(-(yy * yy + xx * xx) * 2.0f);
        sg[p] = g;
        part += g;
    }
#pragma unroll
    for (int off = 32; off > 0; off >>= 1) part += __shfl_down(part, off);
    if ((tid & 63) == 0) sR[tid >> 6] = part;
    __syncthreads();
    float invt = 1.0f / (sR[0] + sR[1] + sR[2] + sR[3]);
    for (int p = tid; p < HW; p += 256) gauss[p] = sg[p] * invt;
}

// ---------------------------------------------------------------------------
// Pack conv weights (fp32 OIHW) into MFMA B-fragment order, split bf16 hi/lo.
// wq[frag][lane][j], frag = ((layer*9+tap)*2 + kstep)*2 + hl, 512 shorts/frag.
// Lane: co = lane&31, half = lane>>5; ci = kstep*16 + half*8 + j.
// Layers 0-2 = rubin rWs, 3-5 = vis vWs.  Total 110592 shorts.
// ---------------------------------------------------------------------------
__global__ __launch_bounds__(256) void prep_w_kernel(
    const float* __restrict__ rWs, const float* __restrict__ vWs,
    unsigned short* __restrict__ wq) {
    int i = blockIdx.x * 256 + threadIdx.x;
    if (i >= 110592) return;
    int j = i & 7;
    int lane = (i >> 3) & 63;
    int f = i >> 9;
    int hl = f & 1, k2 = (f >> 1) & 1, tap = (f >> 2) % 9, layer = (f >> 2) / 9;
    int co = lane & 31, hf = lane >> 5;
    int ci = k2 * 16 + hf * 8 + j;
    int ky = tap / 3, kx = tap % 3;
    float wv = (layer < 3)
        ? rWs[(((size_t)layer * 32 + co) * 32 + ci) * 9 + ky * 3 + kx]
        : vWs[(((size_t)(layer - 3) * 32 + co) * 32 + ci) * 9 + ky * 3 + kx];
    unsigned short h = f2bf(wv);
    unsigned short l = f2bf(wv - bf2f(h));
    wq[i] = hl ? l : h;
}

// ---------------------------------------------------------------------------
// First conv layer (CIN=6 rubin / CIN=1 vis), fp32 VALU. Reads NCHW input,
// writes RAW conv output in swizzled split-bf16 pixel-block Q format:
// per pixel 128B: 8 sub-blocks of 16B (h0-3 = ci groups of 8, l0-3),
// sub-block s stored at ((s + (x&7)) & 7)*16.  Also per-strip GN stats.
// ---------------------------------------------------------------------------
template <int CIN>
__global__ __launch_bounds__(256) void conv_first_kernel(
    const float* __restrict__ in, const float* __restrict__ w,
    unsigned short* __restrict__ qout, float* __restrict__ statp) {
    const int b = blockIdx.y;
    const int strip = blockIdx.x;
    const int tid = threadIdx.x;
    const int x = tid & 63;
    const int wid = tid >> 6;

    __shared__ float sIn[CIN][6][66];
    __shared__ float sRed[4][8];

    const float* inb = in + (size_t)b * CIN * HW;
    for (int idx = tid; idx < CIN * 6 * 66; idx += 256) {
        int ci = idx / (6 * 66);
        int rem = idx - ci * (6 * 66);
        int r = rem / 66;
        int p = rem - r * 66;
        int gy = strip * 4 - 1 + r;
        int gx = p - 1;
        float v = 0.0f;
        if (gy >= 0 && gy < 64 && gx >= 0 && gx < 64) v = inb[ci * HW + gy * 64 + gx];
        sIn[ci][r][p] = v;
    }
    __syncthreads();

    float acc[32];
#pragma unroll
    for (int co = 0; co < 32; ++co) acc[co] = 0.0f;

    for (int ci = 0; ci < CIN; ++ci) {
        float vv[9];
#pragma unroll
        for (int ky = 0; ky < 3; ++ky)
#pragma unroll
            for (int kx = 0; kx < 3; ++kx) vv[ky * 3 + kx] = sIn[ci][wid + ky][x + kx];
#pragma unroll
        for (int co = 0; co < 32; ++co) {
            const float* wk = w + ((size_t)co * CIN + ci) * 9;
            float s = acc[co];
#pragma unroll
            for (int k = 0; k < 9; ++k) s = fmaf(wk[k], vv[k], s);
            acc[co] = s;
        }
    }

    const int gy = strip * 4 + wid;
    // store Q format
    {
        int rot = x & 7;
        char* pb = (char*)qout + (((size_t)b * HW) + (size_t)gy * 64 + x) * 128;
#pragma unroll
        for (int s = 0; s < 4; ++s) {
            unsigned int hw_[4], lw_[4];
#pragma unroll
            for (int e = 0; e < 4; ++e) {
                int c = s * 8 + e * 2;
                unsigned short h0 = f2bf(acc[c]);
                float r0 = acc[c] - bf2f(h0);
                unsigned short h1 = f2bf(acc[c + 1]);
                float r1 = acc[c + 1] - bf2f(h1);
                hw_[e] = (unsigned)h0 | ((unsigned)h1 << 16);
                lw_[e] = (unsigned)f2bf(r0) | ((unsigned)f2bf(r1) << 16);
            }
            uint4 uh; uh.x = hw_[0]; uh.y = hw_[1]; uh.z = hw_[2]; uh.w = hw_[3];
            uint4 ul; ul.x = lw_[0]; ul.y = lw_[1]; ul.z = lw_[2]; ul.w = lw_[3];
            *(uint4*)(pb + (((s + rot) & 7) * 16)) = uh;
            *(uint4*)(pb + (((s + 4 + rot) & 7) * 16)) = ul;
        }
    }
    // stats
    float s1[4] = {0, 0, 0, 0}, s2[4] = {0, 0, 0, 0};
#pragma unroll
    for (int co = 0; co < 32; ++co) {
        float v = acc[co];
        s1[co >> 3] += v;
        s2[co >> 3] = fmaf(v, v, s2[co >> 3]);
    }
#pragma unroll
    for (int off = 32; off > 0; off >>= 1) {
#pragma unroll
        for (int g = 0; g < 4; ++g) {
            s1[g] += __shfl_down(s1[g], off);
            s2[g] += __shfl_down(s2[g], off);
        }
    }
    if ((tid & 63) == 0) {
#pragma unroll
        for (int g = 0; g < 4; ++g) {
            sRed[wid][g] = s1[g];
            sRed[wid][4 + g] = s2[g];
        }
    }
    __syncthreads();
    if (tid < 8) {
        float t = sRed[0][tid] + sRed[1][tid] + sRed[2][tid] + sRed[3][tid];
        statp[((size_t)b * 16 + strip) * 8 + tid] = t;
    }
}

// ---------------------------------------------------------------------------
// GN finalize: per-strip stats -> per-(b,c) affine coefs  y = a*x + b
// ---------------------------------------------------------------------------
__global__ __launch_bounds__(256) void gn_finalize_kernel(
    const float* __restrict__ statp, const float* __restrict__ gma,
    const float* __restrict__ bta, float* __restrict__ coef, int n) {
    int i = blockIdx.x * 256 + threadIdx.x;
    if (i >= n) return;
    int b = i >> 5, c = i & 31, g = c >> 3;
    float s1 = 0.0f, s2 = 0.0f;
    for (int s = 0; s < 16; ++s) {
        s1 += statp[((size_t)b * 16 + s) * 8 + g];
        s2 += statp[((size_t)b * 16 + s) * 8 + 4 + g];
    }
    const float invN = 1.0f / 32768.0f;
    float mean = s1 * invN;
    float var = s2 * invN - mean * mean;
    float rstd = rsqrtf(var + 1e-5f);
    float a = rstd * gma[c];
    float bb = bta[c] - mean * a;
    coef[i * 2 + 0] = a;
    coef[i * 2 + 1] = bb;
}

// ---------------------------------------------------------------------------
// In-place activation on Q: x = h+l; y = gelu(a*x+b); re-split to (h,l).
// Grid (16 px-chunks, bc), thread per pixel.
// ---------------------------------------------------------------------------
__global__ __launch_bounds__(256) void act_kernel(
    unsigned short* __restrict__ q, const float* __restrict__ coef) {
    int b = blockIdx.y, t = threadIdx.x;
    int p = blockIdx.x * 256 + t;
    __shared__ float sc[64];
    if (t < 64) sc[t] = coef[b * 64 + t];
    __syncthreads();
    int rot = p & 7;
    char* pb = (char*)q + (((size_t)b * HW) + p) * 128;
    uint4 uh[4], ul[4];
#pragma unroll
    for (int s = 0; s < 4; ++s) uh[s] = *(const uint4*)(pb + (((s + rot) & 7) * 16));
#pragma unroll
    for (int s = 0; s < 4; ++s) ul[s] = *(const uint4*)(pb + (((s + 4 + rot) & 7) * 16));
#pragma unroll
    for (int s = 0; s < 4; ++s) {
        unsigned int hd[4] = {uh[s].x, uh[s].y, uh[s].z, uh[s].w};
        unsigned int ld[4] = {ul[s].x, ul[s].y, ul[s].z, ul[s].w};
        unsigned int ho[4], lo_[4];
#pragma unroll
        for (int e = 0; e < 4; ++e) {
            int c0 = s * 8 + e * 2;
            float x0 = bf2f((unsigned short)(hd[e] & 0xFFFF)) + bf2f((unsigned short)(ld[e] & 0xFFFF));
            float x1 = bf2f((unsigned short)(hd[e] >> 16)) + bf2f((unsigned short)(ld[e] >> 16));
            float y0 = gelu_f(fmaf(sc[c0 * 2], x0, sc[c0 * 2 + 1]));
            float y1 = gelu_f(fmaf(sc[(c0 + 1) * 2], x1, sc[(c0 + 1) * 2 + 1]));
            unsigned short h0 = f2bf(y0), h1 = f2bf(y1);
            unsigned short l0 = f2bf(y0 - bf2f(h0)), l1 = f2bf(y1 - bf2f(h1));
            ho[e] = (unsigned)h0 | ((unsigned)h1 << 16);
            lo_[e] = (unsigned)l0 | ((unsigned)l1 << 16);
        }
        uint4 oh; oh.x = ho[0]; oh.y = ho[1]; oh.z = ho[2]; oh.w = ho[3];
        uint4 ol; ol.x = lo_[0]; ol.y = lo_[1]; ol.z = lo_[2]; ol.w = lo_[3];
        *(uint4*)(pb + (((s + rot) & 7) * 16)) = oh;
        *(uint4*)(pb + (((s + 4 + rot) & 7) * 16)) = ol;
    }
}

// ---------------------------------------------------------------------------
// MFMA 3x3 conv, CIN=COUT=32, split-bf16 3-term (xh*wh + xh*wl + xl*wh).
// Block = 128 thr = 2 waves (x-halves), strip of 4 output rows; grid (16, bc).
// LDS: 6 staged input rows x 66 slots x 128B (swizzled pixel-blocks).
// Wave = 4 rows x 32 px: 4 C-frags of v_mfma_f32_32x32x16_bf16.
// Writes raw Q (split-bf16) + per-strip GN stats.
// ---------------------------------------------------------------------------
__global__ __launch_bounds__(128) void convm_kernel(
    const unsigned short* __restrict__ qin, const unsigned short* __restrict__ wq,
    unsigned short* __restrict__ qout, float* __restrict__ statp) {
    const int b = blockIdx.y;
    const int strip = blockIdx.x;
    const int tid = threadIdx.x;
    const int wv = tid >> 6;
    const int lane = tid & 63;
    const int m = lane & 31;
    const int hf = lane >> 5;
    const int xh32 = wv * 32;

    __shared__ __align__(16) char sQ[6 * 8448];
    __shared__ float sRed[2][8];

    const int y0 = strip * 4;
    const char* img = (const char*)qin + (size_t)b * HW * 128;
#pragma unroll 6
    for (int k = 0; k < 24; ++k) {
        int c = k * 2 + wv;
        int r = c >> 3;
        int within = (c & 7) * 1024;
        int gy = y0 - 1 + r;
        char* dst = sQ + r * 8448 + 128 + within + lane * 16;
        if (gy >= 0 && gy < 64) {
            *(uint4*)dst = *(const uint4*)(img + (size_t)gy * 8192 + within + lane * 16);
        } else {
            uint4 z; z.x = z.y = z.z = z.w = 0;
            *(uint4*)dst = z;
        }
    }
    if (tid < 96) {
        int pb_ = tid >> 3, sub = tid & 7;
        int r = pb_ >> 1, side = pb_ & 1;
        uint4 z; z.x = z.y = z.z = z.w = 0;
        *(uint4*)(sQ + r * 8448 + side * 8320 + sub * 16) = z;
    }
    __syncthreads();

    f32x16_t acc[4];
#pragma unroll
    for (int i = 0; i < 4; ++i)
#pragma unroll
        for (int j = 0; j < 16; ++j) acc[i][j] = 0.0f;

    for (int kx = 0; kx < 3; ++kx) {
        bf16x8_t Wf[3][2][2];  // [ky][kstep][hl]
#pragma unroll
        for (int ky = 0; ky < 3; ++ky)
#pragma unroll
            for (int k2 = 0; k2 < 2; ++k2)
#pragma unroll
                for (int hl = 0; hl < 2; ++hl) {
                    int fi = ((ky * 3 + kx) * 2 + k2) * 2 + hl;
                    Wf[ky][k2][hl] = __builtin_bit_cast(
                        bf16x8_t, *(const uint4*)(wq + (size_t)fi * 512 + lane * 8));
                }
        const int slotb = xh32 + kx + m;
        const int rot = (m + kx + 7) & 7;
#pragma unroll
        for (int li = 0; li < 6; ++li) {
            const char* rowp = sQ + li * 8448 + slotb * 128;
            bf16x8_t Ah[2], Al[2];
#pragma unroll
            for (int k2 = 0; k2 < 2; ++k2) {
                int sh = k2 * 2 + hf;
                Ah[k2] = __builtin_bit_cast(bf16x8_t, *(const uint4*)(rowp + ((sh + rot) & 7) * 16));
                Al[k2] = __builtin_bit_cast(bf16x8_t, *(const uint4*)(rowp + ((sh + 4 + rot) & 7) * 16));
            }
#pragma unroll
            for (int ky = 0; ky < 3; ++ky) {
                int orow = li - ky;
                if (orow < 0 || orow > 3) continue;
#pragma unroll
                for (int k2 = 0; k2 < 2; ++k2) {
                    acc[orow] = __builtin_amdgcn_mfma_f32_32x32x16_bf16(Ah[k2], Wf[ky][k2][0], acc[orow], 0, 0, 0);
                    acc[orow] = __builtin_amdgcn_mfma_f32_32x32x16_bf16(Ah[k2], Wf[ky][k2][1], acc[orow], 0, 0, 0);
                    acc[orow] = __builtin_amdgcn_mfma_f32_32x32x16_bf16(Al[k2], Wf[ky][k2][0], acc[orow], 0, 0, 0);
                }
            }
        }
    }

    // store raw Q + collect stats
    const int co = lane & 31;
    char* ob = (char*)qout + (size_t)b * HW * 128;
    float s1 = 0.0f, s2 = 0.0f;
#pragma unroll
    for (int orow = 0; orow < 4; ++orow) {
        int y = y0 + orow;
#pragma unroll
        for (int r = 0; r < 16; ++r) {
            int mm = (r & 3) + 8 * (r >> 2) + 4 * hf;
            int x = xh32 + mm;
            float v = acc[orow][r];
            s1 += v;
            s2 = fmaf(v, v, s2);
            unsigned short hv = f2bf(v);
            unsigned short lv = f2bf(v - bf2f(hv));
            int rot2 = mm & 7;
            char* pb = ob + ((size_t)y * 64 + x) * 128;
            *(unsigned short*)(pb + (((co >> 3) + rot2) & 7) * 16 + (co & 7) * 2) = hv;
            *(unsigned short*)(pb + (((co >> 3) + 4 + rot2) & 7) * 16 + (co & 7) * 2) = lv;
        }
    }
    s1 += __shfl_xor(s1, 32); s2 += __shfl_xor(s2, 32);
    s1 += __shfl_xor(s1, 1);  s2 += __shfl_xor(s2, 1);
    s1 += __shfl_xor(s1, 2);  s2 += __shfl_xor(s2, 2);
    s1 += __shfl_xor(s1, 4);  s2 += __shfl_xor(s2, 4);
    if (lane < 32 && (lane & 7) == 0) {
        sRed[wv][co >> 3] = s1;
        sRed[wv][4 + (co >> 3)] = s2;
    }
    __syncthreads();
    if (tid < 8) statp[((size_t)b * 16 + strip) * 8 + tid] = sRed[0][tid] + sRed[1][tid];
}

// ---------------------------------------------------------------------------
// Gauss-pool of ACTIVATED Q: outp[b,c] = sum_p feat(p,c)*gauss(p). Block per b.
// ---------------------------------------------------------------------------
__global__ __launch_bounds__(256) void pool_kernel(
    const unsigned short* __restrict__ q, const float* __restrict__ gauss,
    float* __restrict__ outp) {
    int b = blockIdx.x, t = threadIdx.x;
    __shared__ float red[32][257];
    float acc[32];
#pragma unroll
    for (int c = 0; c < 32; ++c) acc[c] = 0.0f;
    for (int p = t; p < HW; p += 256) {
        float g = gauss[p];
        int rot = p & 7;
        const char* pb = (const char*)q + (((size_t)b * HW) + p) * 128;
#pragma unroll
        for (int s = 0; s < 4; ++s) {
            uint4 uh = *(const uint4*)(pb + (((s + rot) & 7) * 16));
            uint4 ul = *(const uint4*)(pb + (((s + 4 + rot) & 7) * 16));
            unsigned int hd[4] = {uh.x, uh.y, uh.z, uh.w};
            unsigned int ld[4] = {ul.x, ul.y, ul.z, ul.w};
#pragma unroll
            for (int e = 0; e < 4; ++e) {
                int c0 = s * 8 + e * 2;
                float x0 = bf2f((unsigned short)(hd[e] & 0xFFFF)) + bf2f((unsigned short)(ld[e] & 0xFFFF));
                float x1 = bf2f((unsigned short)(hd[e] >> 16)) + bf2f((unsigned short)(ld[e] >> 16));
                acc[c0] = fmaf(x0, g, acc[c0]);
                acc[c0 + 1] = fmaf(x1, g, acc[c0 + 1]);
            }
        }
    }
#pragma unroll
    for (int c = 0; c < 32; ++c) red[c][t] = acc[c];
    __syncthreads();
    if (t < 32) {
        float s = 0.0f;
        for (int i = 0; i < 256; ++i) s += red[t][i];
        outp[b * 32 + t] = s;
    }
}

// ---------------------------------------------------------------------------
// Projection + l2norm from ACTIVATED Q. Writes bf16 NCHW planes (+E, swp).
// ---------------------------------------------------------------------------
__global__ __launch_bounds__(256) void proj_kernel(
    const unsigned short* __restrict__ q, const float* __restrict__ pw,
    unsigned short* __restrict__ outn, float* __restrict__ E,
    float* __restrict__ swp, const float* __restrict__ gauss) {
    int b = blockIdx.y, chunk = blockIdx.x, tid = threadIdx.x;
    int p = chunk * 256 + tid;
    __shared__ float sR[4];
    float feat[32];
    {
        int rot = p & 7;
        const char* pb = (const char*)q + (((size_t)b * HW) + p) * 128;
#pragma unroll
        for (int s = 0; s < 4; ++s) {
            uint4 uh = *(const uint4*)(pb + (((s + rot) & 7) * 16));
            uint4 ul = *(const uint4*)(pb + (((s + 4 + rot) & 7) * 16));
            unsigned int hd[4] = {uh.x, uh.y, uh.z, uh.w};
            unsigned int ld[4] = {ul.x, ul.y, ul.z, ul.w};
#pragma unroll
            for (int e = 0; e < 4; ++e) {
                int c0 = s * 8 + e * 2;
                feat[c0] = bf2f((unsigned short)(hd[e] & 0xFFFF)) + bf2f((unsigned short)(ld[e] & 0xFFFF));
                feat[c0 + 1] = bf2f((unsigned short)(hd[e] >> 16)) + bf2f((unsigned short)(ld[e] >> 16));
            }
        }
    }
    float o[32];
#pragma unroll
    for (int oo = 0; oo < 32; ++oo) o[oo] = 0.0f;
    for (int c = 0; c < 32; ++c) {
        float f = feat[c];
#pragma unroll
        for (int oo = 0; oo < 32; ++oo) o[oo] = fmaf(pw[oo * 32 + c], f, o[oo]);
    }
    float nn = 0.0f;
#pragma unroll
    for (int oo = 0; oo < 32; ++oo) nn = fmaf(o[oo], o[oo], nn);
    float n = sqrtf(nn);
    float inv = 1.0f / fmaxf(n, 1e-6f);
    unsigned short* obp = outn + (size_t)b * 32 * HW + p;
#pragma unroll
    for (int oo = 0; oo < 32; ++oo) obp[(size_t)oo * HW] = f2bf(o[oo] * inv);
    if (E != nullptr) {
        float e = nn * inv * inv;
        E[(size_t)b * HW + p] = e;
        float wvv = e * gauss[p];
#pragma unroll
        for (int off = 32; off > 0; off >>= 1) wvv += __shfl_down(wvv, off);
        if ((tid & 63) == 0) sR[tid >> 6] = wvv;
        __syncthreads();
        if (tid == 0) swp[b * 16 + chunk] = sR[0] + sR[1] + sR[2] + sR[3];
    }
}

// ---------------------------------------------------------------------------
// E <- E * gauss * scale / (sum_p(E*gauss) + 1e-8)
// ---------------------------------------------------------------------------
__global__ __launch_bounds__(256) void swapply_kernel(
    float* __restrict__ E, const float* __restrict__ swp,
    const float* __restrict__ gauss) {
    int b = blockIdx.y, p = blockIdx.x * 256 + threadIdx.x;
    float s = 0.0f;
#pragma unroll
    for (int i = 0; i < 16; ++i) s += swp[b * 16 + i];
    const float scale = 0.17677669529663688f;
    E[(size_t)b * HW + p] = E[(size_t)b * HW + p] * gauss[p] * scale / (s + 1e-8f);
}

// ---------------------------------------------------------------------------
// 49-offset correlation logits, channel-split: grid (bc, 8); each block does
// 4 channels x 2 y-halves and writes a 49-float partial to
// lgpart[(b*8+cg)*49 + k]. head_kernel reduces the 8 partials.
// ---------------------------------------------------------------------------
__global__ __launch_bounds__(256) void logits_kernel(
    const unsigned short* __restrict__ rn, const unsigned short* __restrict__ vn,
    const float* __restrict__ sw, float* __restrict__ lgpart) {
    int b = blockIdx.x, cg = blockIdx.y, tid = threadIdx.x;
    __shared__ float P[38][76];
    __shared__ float sR[4][49];
    float acc[49];
#pragma unroll
    for (int k = 0; k < 49; ++k) acc[k] = 0.0f;
    const float* swb = sw + (size_t)b * HW;
#pragma unroll 1
    for (int cc = 0; cc < 4; ++cc) {
        int c = cg * 4 + cc;
        const unsigned short* vb = vn + ((size_t)b * 32 + c) * HW;
        const unsigned short* rb = rn + ((size_t)b * 32 + c) * HW;
#pragma unroll 1
        for (int half = 0; half < 2; ++half) {
            const int base = half * 32;
            __syncthreads();
            for (int idx = tid; idx < 38 * 72; idx += 256) {
                int r = idx / 72, j = idx - r * 72;
                int gy = base - 3 + r;
                gy = gy < 0 ? 0 : (gy > 63 ? 63 : gy);
                int gx = j - 4;
                gx = gx < 0 ? 0 : (gx > 63 ? 63 : gx);
                P[r][j] = bf2f(vb[gy * 64 + gx]);
            }
            __syncthreads();
            int y = tid >> 3, x0 = (tid & 7) * 8;
            int pbase = (base + y) * 64 + x0;
            uint4 rv = *(const uint4*)(rb + pbase);
            float4 q0 = *(const float4*)(swb + pbase);
            float4 q1 = *(const float4*)(swb + pbase + 4);
            unsigned int rd[4] = {rv.x, rv.y, rv.z, rv.w};
            float r_[8];
            r_[0] = bf2f((unsigned short)(rd[0] & 0xFFFF)) * q0.x;
            r_[1] = bf2f((unsigned short)(rd[0] >> 16)) * q0.y;
            r_[2] = bf2f((unsigned short)(rd[1] & 0xFFFF)) * q0.z;
            r_[3] = bf2f((unsigned short)(rd[1] >> 16)) * q0.w;
            r_[4] = bf2f((unsigned short)(rd[2] & 0xFFFF)) * q1.x;
            r_[5] = bf2f((unsigned short)(rd[2] >> 16)) * q1.y;
            r_[6] = bf2f((unsigned short)(rd[3] & 0xFFFF)) * q1.z;
            r_[7] = bf2f((unsigned short)(rd[3] >> 16)) * q1.w;
#pragma unroll
            for (int dy = 0; dy < 7; ++dy) {
                const float4* Pr = (const float4*)(&P[y + dy][x0]);
                float4 a0 = Pr[0], a1 = Pr[1], a2 = Pr[2], a3 = Pr[3];
                float v[16] = {a0.x, a0.y, a0.z, a0.w, a1.x, a1.y, a1.z, a1.w,
                               a2.x, a2.y, a2.z, a2.w, a3.x, a3.y, a3.z, a3.w};
#pragma unroll
                for (int dx = 0; dx < 7; ++dx) {
#pragma unroll
                    for (int j = 0; j < 8; ++j)
                        acc[dy * 7 + dx] = fmaf(r_[j], v[j + dx + 1], acc[dy * 7 + dx]);
                }
            }
        }
    }
#pragma unroll
    for (int k = 0; k < 49; ++k) {
#pragma unroll
        for (int off = 32; off > 0; off >>= 1) acc[k] += __shfl_down(acc[k], off);
    }
    int wid = tid >> 6;
    __syncthreads();
    if ((tid & 63) == 0) {
#pragma unroll
        for (int k = 0; k < 49; ++k) sR[wid][k] = acc[k];
    }
    __syncthreads();
    if (tid < 49)
        lgpart[((size_t)b * 8 + cg) * 49 + tid] =
            sR[0][tid] + sR[1][tid] + sR[2][tid] + sR[3][tid];
}

// ---------------------------------------------------------------------------
// Softmax/coarse + MLP head + output assembly. Reduces the 8 logit partials.
// ---------------------------------------------------------------------------
__global__ __launch_bounds__(128) void head_kernel(
    const float* __restrict__ lg, const float* __restrict__ rp,
    const float* __restrict__ vp, const float* __restrict__ p2s,
    const float* __restrict__ log_temp,
    const float* __restrict__ W1, const float* __restrict__ b1,
    const float* __restrict__ W2, const float* __restrict__ b2,
    const float* __restrict__ W3, const float* __restrict__ b3,
    float* __restrict__ out) {
    int b = blockIdx.x, t = threadIdx.x;
    __shared__ float slg[49];
    __shared__ float pooled[98];
    __shared__ float h1[128], h2[128];
    __shared__ float cxy[2];
    __shared__ float res[3];
    const float* lgp = lg + (size_t)b * 8 * 49;
    if (t < 49) {
        float s = 0.0f;
#pragma unroll
        for (int g = 0; g < 8; ++g) s += lgp[g * 49 + t];
        slg[t] = s;
    }
    __syncthreads();
    if (t == 0) {
        float temp = fmaxf(expf(log_temp[0]), 0.001f);
        float invT = 1.0f / temp;
        float m = -1e30f;
        for (int k = 0; k < 49; ++k) m = fmaxf(m, slg[k] * invT);
        float s = 0.0f, pdx = 0.0f, pdy = 0.0f;
        for (int k = 0; k < 49; ++k) {
            float e = expf(slg[k] * invT - m);
            s += e;
            pdx += e * (float)((k % 7) - 3);
            pdy += e * (float)((k / 7) - 3);
        }
        cxy[0] = pdx / s;
        cxy[1] = pdy / s;
    }
    __syncthreads();
    if (t < 32) {
        float a = rp[b * 32 + t], c = vp[b * 32 + t];
        pooled[t] = a;
        pooled[32 + t] = c;
        pooled[64 + t] = a - c;
    }
    if (t == 0) {
        pooled[96] = cxy[0];
        pooled[97] = cxy[1];
    }
    __syncthreads();
    float s1 = b1[t];
    for (int i = 0; i < 98; ++i) s1 = fmaf(pooled[i], W1[i * 128 + t], s1);
    h1[t] = gelu_f(s1);
    __syncthreads();
    float s2 = b2[t];
    for (int i = 0; i < 128; ++i) s2 = fmaf(h1[i], W2[i * 128 + t], s2);
    h2[t] = gelu_f(s2);
    __syncthreads();
    if (t < 3) {
        float r = b3[t];
        for (int i = 0; i < 128; ++i) r = fmaf(h2[i], W3[i * 3 + t], r);
        res[t] = r;
    }
    __syncthreads();
    if (t == 0) {
        float dxp = cxy[0] + res[0];
        float dyp = cxy[1] + res[1];
        float ls = fminf(fmaxf(res[2], -6.0f), 3.0f);
        const float* M = p2s + b * 4;
        float* ob = out + b * 54;
        ob[0] = dxp;
        ob[1] = dyp;
        ob[2] = M[0] * dxp + M[1] * dyp;
        ob[3] = M[2] * dxp + M[3] * dyp;
        ob[4] = ls;
    }
    if (t < 49) out[b * 54 + 5 + t] = slg[t];
}

extern "C" void kernel_launch(void* const* d_in, const int* in_sizes, int n_in,
                              void* d_out, int out_size, void* d_ws, size_t ws_size,
                              hipStream_t stream) {
    (void)in_sizes; (void)n_in; (void)out_size;
    const float* rubin = (const float*)d_in[0];
    const float* vis   = (const float*)d_in[1];
    const float* p2s   = (const float*)d_in[2];
    const float* rW0   = (const float*)d_in[3];
    const float* rWs   = (const float*)d_in[4];
    const float* rG    = (const float*)d_in[5];
    const float* rBt   = (const float*)d_in[6];
    const float* vW0   = (const float*)d_in[7];
    const float* vWs   = (const float*)d_in[8];
    const float* vG    = (const float*)d_in[9];
    const float* vBt   = (const float*)d_in[10];
    const float* projR = (const float*)d_in[11];
    const float* projV = (const float*)d_in[12];
    const float* logT  = (const float*)d_in[13];
    const float* W1    = (const float*)d_in[14];
    const float* b1    = (const float*)d_in[15];
    const float* W2    = (const float*)d_in[16];
    const float* b2    = (const float*)d_in[17];
    const float* W3    = (const float*)d_in[18];
    const float* b3    = (const float*)d_in[19];
    float* out = (float*)d_out;

    // ---- workspace layout (bytes)
    char* ws = (char*)d_ws;
    size_t off = 0;
    unsigned short* vnB = (unsigned short*)(ws + off); off += (size_t)NB * 32 * HW * 2;  // 67.1 MB
    float* gauss  = (float*)(ws + off); off += HW * 4;
    float* statp  = (float*)(ws + off); off += (size_t)NB * 16 * 8 * 4;
    float* coefS  = (float*)(ws + off); off += (size_t)NB * 64 * 4;
    float* swp    = (float*)(ws + off); off += (size_t)NB * 16 * 4;
    float* rp     = (float*)(ws + off); off += (size_t)NB * 32 * 4;
    float* vp     = (float*)(ws + off); off += (size_t)NB * 32 * 4;
    float* lgbuf  = (float*)(ws + off); off += (size_t)NB * 8 * 49 * 4;
    unsigned short* wq = (unsigned short*)(ws + off); off += 110592ull * 2;
    off = (off + 255) & ~(size_t)255;
    const size_t fixed_bytes = off;
    const size_t perb = 2ull * HW * 128 + HW * 4;  // Q1+Q2 pixel blocks + E
    int BC = 1;
    if (ws_size > fixed_bytes + perb) {
        size_t t = (ws_size - fixed_bytes) / perb;
        BC = t > (size_t)NB ? NB : (int)t;
    }
    unsigned short* Q1 = (unsigned short*)(ws + off);
    unsigned short* Q2 = (unsigned short*)(ws + off + (size_t)BC * HW * 128);
    float* E = (float*)(ws + off + 2ull * BC * HW * 128);

    dim3 blk256(256), blk128(128);
    gauss_kernel<<<1, 256, 0, stream>>>(gauss);
    prep_w_kernel<<<432, 256, 0, stream>>>(rWs, vWs, wq);

    // ================= VIS encoder (all chunks) =================
    for (int b0 = 0; b0 < NB; b0 += BC) {
        const int bc = (NB - b0) < BC ? (NB - b0) : BC;
        dim3 cg16(16, bc);
        const int gnblk = (bc * 32 + 255) / 256;
        float* sp = statp + (size_t)b0 * 128;
        float* cS = coefS + (size_t)b0 * 64;

        conv_first_kernel<1><<<cg16, blk256, 0, stream>>>(vis + (size_t)b0 * HW, vW0, Q1, sp);
        gn_finalize_kernel<<<gnblk, 256, 0, stream>>>(sp, vG + 0, vBt + 0, cS, bc * 32);
        act_kernel<<<cg16, blk256, 0, stream>>>(Q1, cS);
        convm_kernel<<<cg16, blk128, 0, stream>>>(Q1, wq + 3 * 18432, Q2, sp);
        gn_finalize_kernel<<<gnblk, 256, 0, stream>>>(sp, vG + 32, vBt + 32, cS, bc * 32);
        act_kernel<<<cg16, blk256, 0, stream>>>(Q2, cS);
        convm_kernel<<<cg16, blk128, 0, stream>>>(Q2, wq + 4 * 18432, Q1, sp);
        gn_finalize_kernel<<<gnblk, 256, 0, stream>>>(sp, vG + 64, vBt + 64, cS, bc * 32);
        act_kernel<<<cg16, blk256, 0, stream>>>(Q1, cS);
        convm_kernel<<<cg16, blk128, 0, stream>>>(Q1, wq + 5 * 18432, Q2, sp);
        gn_finalize_kernel<<<gnblk, 256, 0, stream>>>(sp, vG + 96, vBt + 96, cS, bc * 32);
        act_kernel<<<cg16, blk256, 0, stream>>>(Q2, cS);
        pool_kernel<<<bc, blk256, 0, stream>>>(Q2, gauss, vp + (size_t)b0 * 32);
        proj_kernel<<<cg16, blk256, 0, stream>>>(Q2, projV, vnB + (size_t)b0 * 32 * HW,
                                                 (float*)nullptr, (float*)nullptr, gauss);
    }

    // ================= RUBIN encoder + logits (all chunks) =================
    for (int b0 = 0; b0 < NB; b0 += BC) {
        const int bc = (NB - b0) < BC ? (NB - b0) : BC;
        dim3 cg16(16, bc);
        const int gnblk = (bc * 32 + 255) / 256;
        float* sp = statp + (size_t)b0 * 128;
        float* cS = coefS + (size_t)b0 * 64;
        float* sw = swp + (size_t)b0 * 16;
        unsigned short* rnB = Q1;  // dead after last convm reads it

        conv_first_kernel<6><<<cg16, blk256, 0, stream>>>(rubin + (size_t)b0 * 6 * HW, rW0, Q1, sp);
        gn_finalize_kernel<<<gnblk, 256, 0, stream>>>(sp, rG + 0, rBt + 0, cS, bc * 32);
        act_kernel<<<cg16, blk256, 0, stream>>>(Q1, cS);
        convm_kernel<<<cg16, blk128, 0, stream>>>(Q1, wq + 0 * 18432, Q2, sp);
        gn_finalize_kernel<<<gnblk, 256, 0, stream>>>(sp, rG + 32, rBt + 32, cS, bc * 32);
        act_kernel<<<cg16, blk256, 0, stream>>>(Q2, cS);
        convm_kernel<<<cg16, blk128, 0, stream>>>(Q2, wq + 1 * 18432, Q1, sp);
        gn_finalize_kernel<<<gnblk, 256, 0, stream>>>(sp, rG + 64, rBt + 64, cS, bc * 32);
        act_kernel<<<cg16, blk256, 0, stream>>>(Q1, cS);
        convm_kernel<<<cg16, blk128, 0, stream>>>(Q1, wq + 2 * 18432, Q2, sp);
        gn_finalize_kernel<<<gnblk, 256, 0, stream>>>(sp, rG + 96, rBt + 96, cS, bc * 32);
        act_kernel<<<cg16, blk256, 0, stream>>>(Q2, cS);
        pool_kernel<<<bc, blk256, 0, stream>>>(Q2, gauss, rp + (size_t)b0 * 32);
        proj_kernel<<<cg16, blk256, 0, stream>>>(Q2, projR, rnB, E, sw, gauss);
        swapply_kernel<<<cg16, blk256, 0, stream>>>(E, sw, gauss);
        logits_kernel<<<dim3(bc, 8), blk256, 0, stream>>>(rnB, vnB + (size_t)b0 * 32 * HW, E,
                                                          lgbuf + (size_t)b0 * 8 * 49);
    }

    head_kernel<<<NB, 128, 0, stream>>>(lgbuf, rp, vp, p2s, logT, W1, b1, W2, b2, W3, b3, out);
}

// Round 6
// 2125.552 us; speedup vs baseline: 2.8814x; 1.0551x over previous
//
#include <hip/hip_runtime.h>
#include <math.h>

#define HW 4096
#define NB 256

typedef __attribute__((ext_vector_type(8))) short bf16x8_t;
typedef __attribute__((ext_vector_type(16))) float f32x16_t;

__device__ __forceinline__ float gelu_f(float x) {
    return 0.5f * x * (1.0f + erff(x * 0.70710678118654752440f));
}
__device__ __forceinline__ unsigned short f2bf(float f) {
    unsigned int u = __float_as_uint(f);
    unsigned int r = u + 0x7FFFu + ((u >> 16) & 1u);
    return (unsigned short)(r >> 16);
}
__device__ __forceinline__ float bf2f(unsigned short h) {
    return __uint_as_float(((unsigned int)h) << 16);
}

// ---------------------------------------------------------------------------
// Gaussian center window
// ---------------------------------------------------------------------------
__global__ __launch_bounds__(256) void gauss_kernel(float* __restrict__ gauss) {
    __shared__ float sg[HW];
    __shared__ float sR[4];
    int tid = threadIdx.x;
    float part = 0.0f;
    for (int p = tid; p < HW; p += 256) {
        int y = p >> 6, x = p & 63;
        float yy = -1.0f + (2.0f / 63.0f) * (float)y;
        float xx = -1.0f + (2.0f / 63.0f) * (float)x;
        float g = expf(-(yy * yy + xx * xx) * 2.0f);
        sg[p] = g;
        part += g;
    }
#pragma unroll
    for (int off = 32; off > 0; off >>= 1) part += __shfl_down(part, off);
    if ((tid & 63) == 0) sR[tid >> 6] = part;
    __syncthreads();
    float invt = 1.0f / (sR[0] + sR[1] + sR[2] + sR[3]);
    for (int p = tid; p < HW; p += 256) gauss[p] = sg[p] * invt;
}

// ---------------------------------------------------------------------------
// Pack conv weights (fp32 OIHW) into MFMA B-fragment order, split bf16 hi/lo.
// ---------------------------------------------------------------------------
__global__ __launch_bounds__(256) void prep_w_kernel(
    const float* __restrict__ rWs, const float* __restrict__ vWs,
    unsigned short* __restrict__ wq) {
    int i = blockIdx.x * 256 + threadIdx.x;
    if (i >= 110592) return;
    int j = i & 7;
    int lane = (i >> 3) & 63;
    int f = i >> 9;
    int hl = f & 1, k2 = (f >> 1) & 1, tap = (f >> 2) % 9, layer = (f >> 2) / 9;
    int co = lane & 31, hf = lane >> 5;
    int ci = k2 * 16 + hf * 8 + j;
    int ky = tap / 3, kx = tap % 3;
    float wv = (layer < 3)
        ? rWs[(((size_t)layer * 32 + co) * 32 + ci) * 9 + ky * 3 + kx]
        : vWs[(((size_t)(layer - 3) * 32 + co) * 32 + ci) * 9 + ky * 3 + kx];
    unsigned short h = f2bf(wv);
    unsigned short l = f2bf(wv - bf2f(h));
    wq[i] = hl ? l : h;
}

// ---------------------------------------------------------------------------
// First conv layer (CIN=6 rubin / CIN=1 vis), fp32 VALU. Writes RAW Q + stats.
// ---------------------------------------------------------------------------
template <int CIN>
__global__ __launch_bounds__(256) void conv_first_kernel(
    const float* __restrict__ in, const float* __restrict__ w,
    unsigned short* __restrict__ qout, float* __restrict__ statp) {
    const int b = blockIdx.y;
    const int strip = blockIdx.x;
    const int tid = threadIdx.x;
    const int x = tid & 63;
    const int wid = tid >> 6;

    __shared__ float sIn[CIN][6][66];
    __shared__ float sRed[4][8];

    const float* inb = in + (size_t)b * CIN * HW;
    for (int idx = tid; idx < CIN * 6 * 66; idx += 256) {
        int ci = idx / (6 * 66);
        int rem = idx - ci * (6 * 66);
        int r = rem / 66;
        int p = rem - r * 66;
        int gy = strip * 4 - 1 + r;
        int gx = p - 1;
        float v = 0.0f;
        if (gy >= 0 && gy < 64 && gx >= 0 && gx < 64) v = inb[ci * HW + gy * 64 + gx];
        sIn[ci][r][p] = v;
    }
    __syncthreads();

    float acc[32];
#pragma unroll
    for (int co = 0; co < 32; ++co) acc[co] = 0.0f;

    for (int ci = 0; ci < CIN; ++ci) {
        float vv[9];
#pragma unroll
        for (int ky = 0; ky < 3; ++ky)
#pragma unroll
            for (int kx = 0; kx < 3; ++kx) vv[ky * 3 + kx] = sIn[ci][wid + ky][x + kx];
#pragma unroll
        for (int co = 0; co < 32; ++co) {
            const float* wk = w + ((size_t)co * CIN + ci) * 9;
            float s = acc[co];
#pragma unroll
            for (int k = 0; k < 9; ++k) s = fmaf(wk[k], vv[k], s);
            acc[co] = s;
        }
    }

    const int gy = strip * 4 + wid;
    {
        int rot = x & 7;
        char* pb = (char*)qout + (((size_t)b * HW) + (size_t)gy * 64 + x) * 128;
#pragma unroll
        for (int s = 0; s < 4; ++s) {
            unsigned int hw_[4], lw_[4];
#pragma unroll
            for (int e = 0; e < 4; ++e) {
                int c = s * 8 + e * 2;
                unsigned short h0 = f2bf(acc[c]);
                float r0 = acc[c] - bf2f(h0);
                unsigned short h1 = f2bf(acc[c + 1]);
                float r1 = acc[c + 1] - bf2f(h1);
                hw_[e] = (unsigned)h0 | ((unsigned)h1 << 16);
                lw_[e] = (unsigned)f2bf(r0) | ((unsigned)f2bf(r1) << 16);
            }
            uint4 uh; uh.x = hw_[0]; uh.y = hw_[1]; uh.z = hw_[2]; uh.w = hw_[3];
            uint4 ul; ul.x = lw_[0]; ul.y = lw_[1]; ul.z = lw_[2]; ul.w = lw_[3];
            *(uint4*)(pb + (((s + rot) & 7) * 16)) = uh;
            *(uint4*)(pb + (((s + 4 + rot) & 7) * 16)) = ul;
        }
    }
    float s1[4] = {0, 0, 0, 0}, s2[4] = {0, 0, 0, 0};
#pragma unroll
    for (int co = 0; co < 32; ++co) {
        float v = acc[co];
        s1[co >> 3] += v;
        s2[co >> 3] = fmaf(v, v, s2[co >> 3]);
    }
#pragma unroll
    for (int off = 32; off > 0; off >>= 1) {
#pragma unroll
        for (int g = 0; g < 4; ++g) {
            s1[g] += __shfl_down(s1[g], off);
            s2[g] += __shfl_down(s2[g], off);
        }
    }
    if ((tid & 63) == 0) {
#pragma unroll
        for (int g = 0; g < 4; ++g) {
            sRed[wid][g] = s1[g];
            sRed[wid][4 + g] = s2[g];
        }
    }
    __syncthreads();
    if (tid < 8) {
        float t = sRed[0][tid] + sRed[1][tid] + sRed[2][tid] + sRed[3][tid];
        statp[((size_t)b * 16 + strip) * 8 + tid] = t;
    }
}

// ---------------------------------------------------------------------------
// GN finalize: per-strip stats -> per-(b,c) affine coefs  y = a*x + b
// ---------------------------------------------------------------------------
__global__ __launch_bounds__(256) void gn_finalize_kernel(
    const float* __restrict__ statp, const float* __restrict__ gma,
    const float* __restrict__ bta, float* __restrict__ coef, int n) {
    int i = blockIdx.x * 256 + threadIdx.x;
    if (i >= n) return;
    int b = i >> 5, c = i & 31, g = c >> 3;
    float s1 = 0.0f, s2 = 0.0f;
    for (int s = 0; s < 16; ++s) {
        s1 += statp[((size_t)b * 16 + s) * 8 + g];
        s2 += statp[((size_t)b * 16 + s) * 8 + 4 + g];
    }
    const float invN = 1.0f / 32768.0f;
    float mean = s1 * invN;
    float var = s2 * invN - mean * mean;
    float rstd = rsqrtf(var + 1e-5f);
    float a = rstd * gma[c];
    float bb = bta[c] - mean * a;
    coef[i * 2 + 0] = a;
    coef[i * 2 + 1] = bb;
}

// ---------------------------------------------------------------------------
// MFMA 3x3 conv with FUSED input GN+GELU, CIN=COUT=32, split-bf16 3-term.
// Staging: thread owns sub-block s=tid&3; loads (h,l) pair, activates 8
// channels in fp32, re-splits, writes LDS. Values identical to act-then-stage.
// Writes raw Q + per-strip GN stats.
// ---------------------------------------------------------------------------
__global__ __launch_bounds__(128) void convm_kernel(
    const unsigned short* __restrict__ qin, const float* __restrict__ coef,
    const unsigned short* __restrict__ wq,
    unsigned short* __restrict__ qout, float* __restrict__ statp) {
    const int b = blockIdx.y;
    const int strip = blockIdx.x;
    const int tid = threadIdx.x;
    const int wv = tid >> 6;
    const int lane = tid & 63;
    const int m = lane & 31;
    const int hf = lane >> 5;
    const int xh32 = wv * 32;

    __shared__ __align__(16) char sQ[6 * 8448];
    __shared__ float sRed[2][8];

    const int y0 = strip * 4;
    const char* img = (const char*)qin + (size_t)b * HW * 128;

    // per-thread coefs for its fixed sub-block (8 channels)
    const int s_id = tid & 3;
    float ca[8], cb[8];
#pragma unroll
    for (int e = 0; e < 8; ++e) {
        ca[e] = coef[b * 64 + (s_id * 8 + e) * 2 + 0];
        cb[e] = coef[b * 64 + (s_id * 8 + e) * 2 + 1];
    }

#pragma unroll
    for (int it = 0; it < 12; ++it) {
        int idx = it * 128 + tid;
        int r = idx >> 8;             // 0..5
        int px = (idx >> 2) & 63;     // pixel in row
        int gy = y0 - 1 + r;
        int rot = px & 7;
        int offH = ((s_id + rot) & 7) * 16;
        int offL = ((s_id + 4 + rot) & 7) * 16;
        char* dst = sQ + r * 8448 + 128 + px * 128;
        uint4 oh, ol;
        if (gy >= 0 && gy < 64) {
            const char* src = img + (size_t)gy * 8192 + px * 128;
            uint4 uhv = *(const uint4*)(src + offH);
            uint4 ulv = *(const uint4*)(src + offL);
            unsigned int hd[4] = {uhv.x, uhv.y, uhv.z, uhv.w};
            unsigned int ld[4] = {ulv.x, ulv.y, ulv.z, ulv.w};
            unsigned int ho[4], lo_[4];
#pragma unroll
            for (int e = 0; e < 4; ++e) {
                float x0 = bf2f((unsigned short)(hd[e] & 0xFFFF)) + bf2f((unsigned short)(ld[e] & 0xFFFF));
                float x1 = bf2f((unsigned short)(hd[e] >> 16)) + bf2f((unsigned short)(ld[e] >> 16));
                float y0v = gelu_f(fmaf(ca[e * 2], x0, cb[e * 2]));
                float y1v = gelu_f(fmaf(ca[e * 2 + 1], x1, cb[e * 2 + 1]));
                unsigned short h0 = f2bf(y0v), h1 = f2bf(y1v);
                unsigned short l0 = f2bf(y0v - bf2f(h0)), l1 = f2bf(y1v - bf2f(h1));
                ho[e] = (unsigned)h0 | ((unsigned)h1 << 16);
                lo_[e] = (unsigned)l0 | ((unsigned)l1 << 16);
            }
            oh.x = ho[0]; oh.y = ho[1]; oh.z = ho[2]; oh.w = ho[3];
            ol.x = lo_[0]; ol.y = lo_[1]; ol.z = lo_[2]; ol.w = lo_[3];
        } else {
            oh.x = oh.y = oh.z = oh.w = 0;
            ol.x = ol.y = ol.z = ol.w = 0;
        }
        *(uint4*)(dst + offH) = oh;
        *(uint4*)(dst + offL) = ol;
    }
    if (tid < 96) {
        int pb_ = tid >> 3, sub = tid & 7;
        int r = pb_ >> 1, side = pb_ & 1;
        uint4 z; z.x = z.y = z.z = z.w = 0;
        *(uint4*)(sQ + r * 8448 + side * 8320 + sub * 16) = z;
    }
    __syncthreads();

    f32x16_t acc[4];
#pragma unroll
    for (int i = 0; i < 4; ++i)
#pragma unroll
        for (int j = 0; j < 16; ++j) acc[i][j] = 0.0f;

    for (int kx = 0; kx < 3; ++kx) {
        bf16x8_t Wf[3][2][2];  // [ky][kstep][hl]
#pragma unroll
        for (int ky = 0; ky < 3; ++ky)
#pragma unroll
            for (int k2 = 0; k2 < 2; ++k2)
#pragma unroll
                for (int hl = 0; hl < 2; ++hl) {
                    int fi = ((ky * 3 + kx) * 2 + k2) * 2 + hl;
                    Wf[ky][k2][hl] = __builtin_bit_cast(
                        bf16x8_t, *(const uint4*)(wq + (size_t)fi * 512 + lane * 8));
                }
        const int slotb = xh32 + kx + m;
        const int rot = (m + kx + 7) & 7;
#pragma unroll
        for (int li = 0; li < 6; ++li) {
            const char* rowp = sQ + li * 8448 + slotb * 128;
            bf16x8_t Ah[2], Al[2];
#pragma unroll
            for (int k2 = 0; k2 < 2; ++k2) {
                int sh = k2 * 2 + hf;
                Ah[k2] = __builtin_bit_cast(bf16x8_t, *(const uint4*)(rowp + ((sh + rot) & 7) * 16));
                Al[k2] = __builtin_bit_cast(bf16x8_t, *(const uint4*)(rowp + ((sh + 4 + rot) & 7) * 16));
            }
#pragma unroll
            for (int ky = 0; ky < 3; ++ky) {
                int orow = li - ky;
                if (orow < 0 || orow > 3) continue;
#pragma unroll
                for (int k2 = 0; k2 < 2; ++k2) {
                    acc[orow] = __builtin_amdgcn_mfma_f32_32x32x16_bf16(Ah[k2], Wf[ky][k2][0], acc[orow], 0, 0, 0);
                    acc[orow] = __builtin_amdgcn_mfma_f32_32x32x16_bf16(Ah[k2], Wf[ky][k2][1], acc[orow], 0, 0, 0);
                    acc[orow] = __builtin_amdgcn_mfma_f32_32x32x16_bf16(Al[k2], Wf[ky][k2][0], acc[orow], 0, 0, 0);
                }
            }
        }
    }

    // store raw Q + collect stats
    const int co = lane & 31;
    char* ob = (char*)qout + (size_t)b * HW * 128;
    float s1 = 0.0f, s2 = 0.0f;
#pragma unroll
    for (int orow = 0; orow < 4; ++orow) {
        int y = y0 + orow;
#pragma unroll
        for (int r = 0; r < 16; ++r) {
            int mm = (r & 3) + 8 * (r >> 2) + 4 * hf;
            int x = xh32 + mm;
            float v = acc[orow][r];
            s1 += v;
            s2 = fmaf(v, v, s2);
            unsigned short hv = f2bf(v);
            unsigned short lv = f2bf(v - bf2f(hv));
            int rot2 = mm & 7;
            char* pb = ob + ((size_t)y * 64 + x) * 128;
            *(unsigned short*)(pb + (((co >> 3) + rot2) & 7) * 16 + (co & 7) * 2) = hv;
            *(unsigned short*)(pb + (((co >> 3) + 4 + rot2) & 7) * 16 + (co & 7) * 2) = lv;
        }
    }
    s1 += __shfl_xor(s1, 32); s2 += __shfl_xor(s2, 32);
    s1 += __shfl_xor(s1, 1);  s2 += __shfl_xor(s2, 1);
    s1 += __shfl_xor(s1, 2);  s2 += __shfl_xor(s2, 2);
    s1 += __shfl_xor(s1, 4);  s2 += __shfl_xor(s2, 4);
    if (lane < 32 && (lane & 7) == 0) {
        sRed[wv][co >> 3] = s1;
        sRed[wv][4 + (co >> 3)] = s2;
    }
    __syncthreads();
    if (tid < 8) statp[((size_t)b * 16 + strip) * 8 + tid] = sRed[0][tid] + sRed[1][tid];
}

// ---------------------------------------------------------------------------
// Gauss-pool of RAW Q with fused GN+GELU: outp[b,c] = sum_p gelu(a*x+b)*g(p).
// ---------------------------------------------------------------------------
__global__ __launch_bounds__(256) void pool_kernel(
    const unsigned short* __restrict__ q, const float* __restrict__ coef,
    const float* __restrict__ gauss, float* __restrict__ outp) {
    int b = blockIdx.x, t = threadIdx.x;
    __shared__ float red[32][257];
    __shared__ float sc[64];
    if (t < 64) sc[t] = coef[b * 64 + t];
    __syncthreads();
    float acc[32];
#pragma unroll
    for (int c = 0; c < 32; ++c) acc[c] = 0.0f;
    for (int p = t; p < HW; p += 256) {
        float g = gauss[p];
        int rot = p & 7;
        const char* pb = (const char*)q + (((size_t)b * HW) + p) * 128;
#pragma unroll
        for (int s = 0; s < 4; ++s) {
            uint4 uh = *(const uint4*)(pb + (((s + rot) & 7) * 16));
            uint4 ul = *(const uint4*)(pb + (((s + 4 + rot) & 7) * 16));
            unsigned int hd[4] = {uh.x, uh.y, uh.z, uh.w};
            unsigned int ld[4] = {ul.x, ul.y, ul.z, ul.w};
#pragma unroll
            for (int e = 0; e < 4; ++e) {
                int c0 = s * 8 + e * 2;
                float x0 = bf2f((unsigned short)(hd[e] & 0xFFFF)) + bf2f((unsigned short)(ld[e] & 0xFFFF));
                float x1 = bf2f((unsigned short)(hd[e] >> 16)) + bf2f((unsigned short)(ld[e] >> 16));
                float y0 = gelu_f(fmaf(sc[c0 * 2], x0, sc[c0 * 2 + 1]));
                float y1 = gelu_f(fmaf(sc[(c0 + 1) * 2], x1, sc[(c0 + 1) * 2 + 1]));
                acc[c0] = fmaf(y0, g, acc[c0]);
                acc[c0 + 1] = fmaf(y1, g, acc[c0 + 1]);
            }
        }
    }
#pragma unroll
    for (int c = 0; c < 32; ++c) red[c][t] = acc[c];
    __syncthreads();
    if (t < 32) {
        float s = 0.0f;
        for (int i = 0; i < 256; ++i) s += red[t][i];
        outp[b * 32 + t] = s;
    }
}

// ---------------------------------------------------------------------------
// Projection + l2norm from RAW Q with fused GN+GELU. Writes bf16 NCHW (+E,swp).
// ---------------------------------------------------------------------------
__global__ __launch_bounds__(256) void proj_kernel(
    const unsigned short* __restrict__ q, const float* __restrict__ coef,
    const float* __restrict__ pw, unsigned short* __restrict__ outn,
    float* __restrict__ E, float* __restrict__ swp,
    const float* __restrict__ gauss) {
    int b = blockIdx.y, chunk = blockIdx.x, tid = threadIdx.x;
    int p = chunk * 256 + tid;
    __shared__ float sR[4];
    __shared__ float sc[64];
    if (tid < 64) sc[tid] = coef[b * 64 + tid];
    __syncthreads();
    float feat[32];
    {
        int rot = p & 7;
        const char* pb = (const char*)q + (((size_t)b * HW) + p) * 128;
#pragma unroll
        for (int s = 0; s < 4; ++s) {
            uint4 uh = *(const uint4*)(pb + (((s + rot) & 7) * 16));
            uint4 ul = *(const uint4*)(pb + (((s + 4 + rot) & 7) * 16));
            unsigned int hd[4] = {uh.x, uh.y, uh.z, uh.w};
            unsigned int ld[4] = {ul.x, ul.y, ul.z, ul.w};
#pragma unroll
            for (int e = 0; e < 4; ++e) {
                int c0 = s * 8 + e * 2;
                float x0 = bf2f((unsigned short)(hd[e] & 0xFFFF)) + bf2f((unsigned short)(ld[e] & 0xFFFF));
                float x1 = bf2f((unsigned short)(hd[e] >> 16)) + bf2f((unsigned short)(ld[e] >> 16));
                feat[c0] = gelu_f(fmaf(sc[c0 * 2], x0, sc[c0 * 2 + 1]));
                feat[c0 + 1] = gelu_f(fmaf(sc[(c0 + 1) * 2], x1, sc[(c0 + 1) * 2 + 1]));
            }
        }
    }
    float o[32];
#pragma unroll
    for (int oo = 0; oo < 32; ++oo) o[oo] = 0.0f;
    for (int c = 0; c < 32; ++c) {
        float f = feat[c];
#pragma unroll
        for (int oo = 0; oo < 32; ++oo) o[oo] = fmaf(pw[oo * 32 + c], f, o[oo]);
    }
    float nn = 0.0f;
#pragma unroll
    for (int oo = 0; oo < 32; ++oo) nn = fmaf(o[oo], o[oo], nn);
    float n = sqrtf(nn);
    float inv = 1.0f / fmaxf(n, 1e-6f);
    unsigned short* obp = outn + (size_t)b * 32 * HW + p;
#pragma unroll
    for (int oo = 0; oo < 32; ++oo) obp[(size_t)oo * HW] = f2bf(o[oo] * inv);
    if (E != nullptr) {
        float e = nn * inv * inv;
        E[(size_t)b * HW + p] = e;
        float wvv = e * gauss[p];
#pragma unroll
        for (int off = 32; off > 0; off >>= 1) wvv += __shfl_down(wvv, off);
        if ((tid & 63) == 0) sR[tid >> 6] = wvv;
        __syncthreads();
        if (tid == 0) swp[b * 16 + chunk] = sR[0] + sR[1] + sR[2] + sR[3];
    }
}

// ---------------------------------------------------------------------------
// E <- E * gauss * scale / (sum_p(E*gauss) + 1e-8)
// ---------------------------------------------------------------------------
__global__ __launch_bounds__(256) void swapply_kernel(
    float* __restrict__ E, const float* __restrict__ swp,
    const float* __restrict__ gauss) {
    int b = blockIdx.y, p = blockIdx.x * 256 + threadIdx.x;
    float s = 0.0f;
#pragma unroll
    for (int i = 0; i < 16; ++i) s += swp[b * 16 + i];
    const float scale = 0.17677669529663688f;
    E[(size_t)b * HW + p] = E[(size_t)b * HW + p] * gauss[p] * scale / (s + 1e-8f);
}

// ---------------------------------------------------------------------------
// 49-offset correlation logits, channel-split: grid (bc, 8).
// ---------------------------------------------------------------------------
__global__ __launch_bounds__(256) void logits_kernel(
    const unsigned short* __restrict__ rn, const unsigned short* __restrict__ vn,
    const float* __restrict__ sw, float* __restrict__ lgpart) {
    int b = blockIdx.x, cg = blockIdx.y, tid = threadIdx.x;
    __shared__ float P[38][76];
    __shared__ float sR[4][49];
    float acc[49];
#pragma unroll
    for (int k = 0; k < 49; ++k) acc[k] = 0.0f;
    const float* swb = sw + (size_t)b * HW;
#pragma unroll 1
    for (int cc = 0; cc < 4; ++cc) {
        int c = cg * 4 + cc;
        const unsigned short* vb = vn + ((size_t)b * 32 + c) * HW;
        const unsigned short* rb = rn + ((size_t)b * 32 + c) * HW;
#pragma unroll 1
        for (int half = 0; half < 2; ++half) {
            const int base = half * 32;
            __syncthreads();
            for (int idx = tid; idx < 38 * 72; idx += 256) {
                int r = idx / 72, j = idx - r * 72;
                int gy = base - 3 + r;
                gy = gy < 0 ? 0 : (gy > 63 ? 63 : gy);
                int gx = j - 4;
                gx = gx < 0 ? 0 : (gx > 63 ? 63 : gx);
                P[r][j] = bf2f(vb[gy * 64 + gx]);
            }
            __syncthreads();
            int y = tid >> 3, x0 = (tid & 7) * 8;
            int pbase = (base + y) * 64 + x0;
            uint4 rv = *(const uint4*)(rb + pbase);
            float4 q0 = *(const float4*)(swb + pbase);
            float4 q1 = *(const float4*)(swb + pbase + 4);
            unsigned int rd[4] = {rv.x, rv.y, rv.z, rv.w};
            float r_[8];
            r_[0] = bf2f((unsigned short)(rd[0] & 0xFFFF)) * q0.x;
            r_[1] = bf2f((unsigned short)(rd[0] >> 16)) * q0.y;
            r_[2] = bf2f((unsigned short)(rd[1] & 0xFFFF)) * q0.z;
            r_[3] = bf2f((unsigned short)(rd[1] >> 16)) * q0.w;
            r_[4] = bf2f((unsigned short)(rd[2] & 0xFFFF)) * q1.x;
            r_[5] = bf2f((unsigned short)(rd[2] >> 16)) * q1.y;
            r_[6] = bf2f((unsigned short)(rd[3] & 0xFFFF)) * q1.z;
            r_[7] = bf2f((unsigned short)(rd[3] >> 16)) * q1.w;
#pragma unroll
            for (int dy = 0; dy < 7; ++dy) {
                const float4* Pr = (const float4*)(&P[y + dy][x0]);
                float4 a0 = Pr[0], a1 = Pr[1], a2 = Pr[2], a3 = Pr[3];
                float v[16] = {a0.x, a0.y, a0.z, a0.w, a1.x, a1.y, a1.z, a1.w,
                               a2.x, a2.y, a2.z, a2.w, a3.x, a3.y, a3.z, a3.w};
#pragma unroll
                for (int dx = 0; dx < 7; ++dx) {
#pragma unroll
                    for (int j = 0; j < 8; ++j)
                        acc[dy * 7 + dx] = fmaf(r_[j], v[j + dx + 1], acc[dy * 7 + dx]);
                }
            }
        }
    }
#pragma unroll
    for (int k = 0; k < 49; ++k) {
#pragma unroll
        for (int off = 32; off > 0; off >>= 1) acc[k] += __shfl_down(acc[k], off);
    }
    int wid = tid >> 6;
    __syncthreads();
    if ((tid & 63) == 0) {
#pragma unroll
        for (int k = 0; k < 49; ++k) sR[wid][k] = acc[k];
    }
    __syncthreads();
    if (tid < 49)
        lgpart[((size_t)b * 8 + cg) * 49 + tid] =
            sR[0][tid] + sR[1][tid] + sR[2][tid] + sR[3][tid];
}

// ---------------------------------------------------------------------------
// Softmax/coarse + MLP head + output assembly. Reduces the 8 logit partials.
// ---------------------------------------------------------------------------
__global__ __launch_bounds__(128) void head_kernel(
    const float* __restrict__ lg, const float* __restrict__ rp,
    const float* __restrict__ vp, const float* __restrict__ p2s,
    const float* __restrict__ log_temp,
    const float* __restrict__ W1, const float* __restrict__ b1,
    const float* __restrict__ W2, const float* __restrict__ b2,
    const float* __restrict__ W3, const float* __restrict__ b3,
    float* __restrict__ out) {
    int b = blockIdx.x, t = threadIdx.x;
    __shared__ float slg[49];
    __shared__ float pooled[98];
    __shared__ float h1[128], h2[128];
    __shared__ float cxy[2];
    __shared__ float res[3];
    const float* lgp = lg + (size_t)b * 8 * 49;
    if (t < 49) {
        float s = 0.0f;
#pragma unroll
        for (int g = 0; g < 8; ++g) s += lgp[g * 49 + t];
        slg[t] = s;
    }
    __syncthreads();
    if (t == 0) {
        float temp = fmaxf(expf(log_temp[0]), 0.001f);
        float invT = 1.0f / temp;
        float m = -1e30f;
        for (int k = 0; k < 49; ++k) m = fmaxf(m, slg[k] * invT);
        float s = 0.0f, pdx = 0.0f, pdy = 0.0f;
        for (int k = 0; k < 49; ++k) {
            float e = expf(slg[k] * invT - m);
            s += e;
            pdx += e * (float)((k % 7) - 3);
            pdy += e * (float)((k / 7) - 3);
        }
        cxy[0] = pdx / s;
        cxy[1] = pdy / s;
    }
    __syncthreads();
    if (t < 32) {
        float a = rp[b * 32 + t], c = vp[b * 32 + t];
        pooled[t] = a;
        pooled[32 + t] = c;
        pooled[64 + t] = a - c;
    }
    if (t == 0) {
        pooled[96] = cxy[0];
        pooled[97] = cxy[1];
    }
    __syncthreads();
    float s1 = b1[t];
    for (int i = 0; i < 98; ++i) s1 = fmaf(pooled[i], W1[i * 128 + t], s1);
    h1[t] = gelu_f(s1);
    __syncthreads();
    float s2 = b2[t];
    for (int i = 0; i < 128; ++i) s2 = fmaf(h1[i], W2[i * 128 + t], s2);
    h2[t] = gelu_f(s2);
    __syncthreads();
    if (t < 3) {
        float r = b3[t];
        for (int i = 0; i < 128; ++i) r = fmaf(h2[i], W3[i * 3 + t], r);
        res[t] = r;
    }
    __syncthreads();
    if (t == 0) {
        float dxp = cxy[0] + res[0];
        float dyp = cxy[1] + res[1];
        float ls = fminf(fmaxf(res[2], -6.0f), 3.0f);
        const float* M = p2s + b * 4;
        float* ob = out + b * 54;
        ob[0] = dxp;
        ob[1] = dyp;
        ob[2] = M[0] * dxp + M[1] * dyp;
        ob[3] = M[2] * dxp + M[3] * dyp;
        ob[4] = ls;
    }
    if (t < 49) out[b * 54 + 5 + t] = slg[t];
}

extern "C" void kernel_launch(void* const* d_in, const int* in_sizes, int n_in,
                              void* d_out, int out_size, void* d_ws, size_t ws_size,
                              hipStream_t stream) {
    (void)in_sizes; (void)n_in; (void)out_size;
    const float* rubin = (const float*)d_in[0];
    const float* vis   = (const float*)d_in[1];
    const float* p2s   = (const float*)d_in[2];
    const float* rW0   = (const float*)d_in[3];
    const float* rWs   = (const float*)d_in[4];
    const float* rG    = (const float*)d_in[5];
    const float* rBt   = (const float*)d_in[6];
    const float* vW0   = (const float*)d_in[7];
    const float* vWs   = (const float*)d_in[8];
    const float* vG    = (const float*)d_in[9];
    const float* vBt   = (const float*)d_in[10];
    const float* projR = (const float*)d_in[11];
    const float* projV = (const float*)d_in[12];
    const float* logT  = (const float*)d_in[13];
    const float* W1    = (const float*)d_in[14];
    const float* b1    = (const float*)d_in[15];
    const float* W2    = (const float*)d_in[16];
    const float* b2    = (const float*)d_in[17];
    const float* W3    = (const float*)d_in[18];
    const float* b3    = (const float*)d_in[19];
    float* out = (float*)d_out;

    // ---- workspace layout (bytes)
    char* ws = (char*)d_ws;
    size_t off = 0;
    unsigned short* vnB = (unsigned short*)(ws + off); off += (size_t)NB * 32 * HW * 2;  // 67.1 MB
    float* gauss  = (float*)(ws + off); off += HW * 4;
    float* statp  = (float*)(ws + off); off += (size_t)NB * 16 * 8 * 4;
    float* coefS  = (float*)(ws + off); off += (size_t)NB * 64 * 4;
    float* swp    = (float*)(ws + off); off += (size_t)NB * 16 * 4;
    float* rp     = (float*)(ws + off); off += (size_t)NB * 32 * 4;
    float* vp     = (float*)(ws + off); off += (size_t)NB * 32 * 4;
    float* lgbuf  = (float*)(ws + off); off += (size_t)NB * 8 * 49 * 4;
    unsigned short* wq = (unsigned short*)(ws + off); off += 110592ull * 2;
    off = (off + 255) & ~(size_t)255;
    const size_t fixed_bytes = off;
    const size_t perb = 2ull * HW * 128 + HW * 4;  // Q1+Q2 pixel blocks + E
    int BC = 1;
    if (ws_size > fixed_bytes + perb) {
        size_t t = (ws_size - fixed_bytes) / perb;
        BC = t > (size_t)NB ? NB : (int)t;
    }
    unsigned short* Q1 = (unsigned short*)(ws + off);
    unsigned short* Q2 = (unsigned short*)(ws + off + (size_t)BC * HW * 128);
    float* E = (float*)(ws + off + 2ull * BC * HW * 128);

    dim3 blk256(256), blk128(128);
    gauss_kernel<<<1, 256, 0, stream>>>(gauss);
    prep_w_kernel<<<432, 256, 0, stream>>>(rWs, vWs, wq);

    // ================= VIS encoder (all chunks) =================
    for (int b0 = 0; b0 < NB; b0 += BC) {
        const int bc = (NB - b0) < BC ? (NB - b0) : BC;
        dim3 cg16(16, bc);
        const int gnblk = (bc * 32 + 255) / 256;
        float* sp = statp + (size_t)b0 * 128;
        float* cS = coefS + (size_t)b0 * 64;

        conv_first_kernel<1><<<cg16, blk256, 0, stream>>>(vis + (size_t)b0 * HW, vW0, Q1, sp);
        gn_finalize_kernel<<<gnblk, 256, 0, stream>>>(sp, vG + 0, vBt + 0, cS, bc * 32);
        convm_kernel<<<cg16, blk128, 0, stream>>>(Q1, cS, wq + 3 * 18432, Q2, sp);
        gn_finalize_kernel<<<gnblk, 256, 0, stream>>>(sp, vG + 32, vBt + 32, cS, bc * 32);
        convm_kernel<<<cg16, blk128, 0, stream>>>(Q2, cS, wq + 4 * 18432, Q1, sp);
        gn_finalize_kernel<<<gnblk, 256, 0, stream>>>(sp, vG + 64, vBt + 64, cS, bc * 32);
        convm_kernel<<<cg16, blk128, 0, stream>>>(Q1, cS, wq + 5 * 18432, Q2, sp);
        gn_finalize_kernel<<<gnblk, 256, 0, stream>>>(sp, vG + 96, vBt + 96, cS, bc * 32);
        pool_kernel<<<bc, blk256, 0, stream>>>(Q2, cS, gauss, vp + (size_t)b0 * 32);
        proj_kernel<<<cg16, blk256, 0, stream>>>(Q2, cS, projV, vnB + (size_t)b0 * 32 * HW,
                                                 (float*)nullptr, (float*)nullptr, gauss);
    }

    // ================= RUBIN encoder + logits (all chunks) =================
    for (int b0 = 0; b0 < NB; b0 += BC) {
        const int bc = (NB - b0) < BC ? (NB - b0) : BC;
        dim3 cg16(16, bc);
        const int gnblk = (bc * 32 + 255) / 256;
        float* sp = statp + (size_t)b0 * 128;
        float* cS = coefS + (size_t)b0 * 64;
        float* sw = swp + (size_t)b0 * 16;
        unsigned short* rnB = Q1;  // dead after last convm reads it

        conv_first_kernel<6><<<cg16, blk256, 0, stream>>>(rubin + (size_t)b0 * 6 * HW, rW0, Q1, sp);
        gn_finalize_kernel<<<gnblk, 256, 0, stream>>>(sp, rG + 0, rBt + 0, cS, bc * 32);
        convm_kernel<<<cg16, blk128, 0, stream>>>(Q1, cS, wq + 0 * 18432, Q2, sp);
        gn_finalize_kernel<<<gnblk, 256, 0, stream>>>(sp, rG + 32, rBt + 32, cS, bc * 32);
        convm_kernel<<<cg16, blk128, 0, stream>>>(Q2, cS, wq + 1 * 18432, Q1, sp);
        gn_finalize_kernel<<<gnblk, 256, 0, stream>>>(sp, rG + 64, rBt + 64, cS, bc * 32);
        convm_kernel<<<cg16, blk128, 0, stream>>>(Q1, cS, wq + 2 * 18432, Q2, sp);
        gn_finalize_kernel<<<gnblk, 256, 0, stream>>>(sp, rG + 96, rBt + 96, cS, bc * 32);
        pool_kernel<<<bc, blk256, 0, stream>>>(Q2, cS, gauss, rp + (size_t)b0 * 32);
        proj_kernel<<<cg16, blk256, 0, stream>>>(Q2, cS, projR, rnB, E, sw, gauss);
        swapply_kernel<<<cg16, blk256, 0, stream>>>(E, sw, gauss);
        logits_kernel<<<dim3(bc, 8), blk256, 0, stream>>>(rnB, vnB + (size_t)b0 * 32 * HW, E,
                                                          lgbuf + (size_t)b0 * 8 * 49);
    }

    head_kernel<<<NB, 128, 0, stream>>>(lgbuf, rp, vp, p2s, logT, W1, b1, W2, b2, W3, b3, out);
}

// Round 7
// 1921.364 us; speedup vs baseline: 3.1876x; 1.1063x over previous
//
#include <hip/hip_runtime.h>
#include <math.h>

#define HW 4096
#define NB 256

typedef __attribute__((ext_vector_type(8))) short bf16x8_t;
typedef __attribute__((ext_vector_type(16))) float f32x16_t;

__device__ __forceinline__ float gelu_f(float x) {
    return 0.5f * x * (1.0f + erff(x * 0.70710678118654752440f));
}
__device__ __forceinline__ unsigned short f2bf(float f) {
    unsigned int u = __float_as_uint(f);
    unsigned int r = u + 0x7FFFu + ((u >> 16) & 1u);
    return (unsigned short)(r >> 16);
}
__device__ __forceinline__ float bf2f(unsigned short h) {
    return __uint_as_float(((unsigned int)h) << 16);
}

// ---------------------------------------------------------------------------
// Gaussian center window
// ---------------------------------------------------------------------------
__global__ __launch_bounds__(256) void gauss_kernel(float* __restrict__ gauss) {
    __shared__ float sg[HW];
    __shared__ float sR[4];
    int tid = threadIdx.x;
    float part = 0.0f;
    for (int p = tid; p < HW; p += 256) {
        int y = p >> 6, x = p & 63;
        float yy = -1.0f + (2.0f / 63.0f) * (float)y;
        float xx = -1.0f + (2.0f / 63.0f) * (float)x;
        float g = expf(-(yy * yy + xx * xx) * 2.0f);
        sg[p] = g;
        part += g;
    }
#pragma unroll
    for (int off = 32; off > 0; off >>= 1) part += __shfl_down(part, off);
    if ((tid & 63) == 0) sR[tid >> 6] = part;
    __syncthreads();
    float invt = 1.0f / (sR[0] + sR[1] + sR[2] + sR[3]);
    for (int p = tid; p < HW; p += 256) gauss[p] = sg[p] * invt;
}

// ---------------------------------------------------------------------------
// Pack conv weights (fp32 OIHW) into MFMA B-fragment order, split bf16 hi/lo.
// ---------------------------------------------------------------------------
__global__ __launch_bounds__(256) void prep_w_kernel(
    const float* __restrict__ rWs, const float* __restrict__ vWs,
    unsigned short* __restrict__ wq) {
    int i = blockIdx.x * 256 + threadIdx.x;
    if (i >= 110592) return;
    int j = i & 7;
    int lane = (i >> 3) & 63;
    int f = i >> 9;
    int hl = f & 1, k2 = (f >> 1) & 1, tap = (f >> 2) % 9, layer = (f >> 2) / 9;
    int co = lane & 31, hf = lane >> 5;
    int ci = k2 * 16 + hf * 8 + j;
    int ky = tap / 3, kx = tap % 3;
    float wv = (layer < 3)
        ? rWs[(((size_t)layer * 32 + co) * 32 + ci) * 9 + ky * 3 + kx]
        : vWs[(((size_t)(layer - 3) * 32 + co) * 32 + ci) * 9 + ky * 3 + kx];
    unsigned short h = f2bf(wv);
    unsigned short l = f2bf(wv - bf2f(h));
    wq[i] = hl ? l : h;
}

// ---------------------------------------------------------------------------
// First conv layer (CIN=6 rubin / CIN=1 vis), fp32 VALU. Writes RAW Q + stats.
// ---------------------------------------------------------------------------
template <int CIN>
__global__ __launch_bounds__(256) void conv_first_kernel(
    const float* __restrict__ in, const float* __restrict__ w,
    unsigned short* __restrict__ qout, float* __restrict__ statp) {
    const int b = blockIdx.y;
    const int strip = blockIdx.x;
    const int tid = threadIdx.x;
    const int x = tid & 63;
    const int wid = tid >> 6;

    __shared__ float sIn[CIN][6][66];
    __shared__ float sRed[4][8];

    const float* inb = in + (size_t)b * CIN * HW;
    for (int idx = tid; idx < CIN * 6 * 66; idx += 256) {
        int ci = idx / (6 * 66);
        int rem = idx - ci * (6 * 66);
        int r = rem / 66;
        int p = rem - r * 66;
        int gy = strip * 4 - 1 + r;
        int gx = p - 1;
        float v = 0.0f;
        if (gy >= 0 && gy < 64 && gx >= 0 && gx < 64) v = inb[ci * HW + gy * 64 + gx];
        sIn[ci][r][p] = v;
    }
    __syncthreads();

    float acc[32];
#pragma unroll
    for (int co = 0; co < 32; ++co) acc[co] = 0.0f;

    for (int ci = 0; ci < CIN; ++ci) {
        float vv[9];
#pragma unroll
        for (int ky = 0; ky < 3; ++ky)
#pragma unroll
            for (int kx = 0; kx < 3; ++kx) vv[ky * 3 + kx] = sIn[ci][wid + ky][x + kx];
#pragma unroll
        for (int co = 0; co < 32; ++co) {
            const float* wk = w + ((size_t)co * CIN + ci) * 9;
            float s = acc[co];
#pragma unroll
            for (int k = 0; k < 9; ++k) s = fmaf(wk[k], vv[k], s);
            acc[co] = s;
        }
    }

    const int gy = strip * 4 + wid;
    {
        int rot = x & 7;
        char* pb = (char*)qout + (((size_t)b * HW) + (size_t)gy * 64 + x) * 128;
#pragma unroll
        for (int s = 0; s < 4; ++s) {
            unsigned int hw_[4], lw_[4];
#pragma unroll
            for (int e = 0; e < 4; ++e) {
                int c = s * 8 + e * 2;
                unsigned short h0 = f2bf(acc[c]);
                float r0 = acc[c] - bf2f(h0);
                unsigned short h1 = f2bf(acc[c + 1]);
                float r1 = acc[c + 1] - bf2f(h1);
                hw_[e] = (unsigned)h0 | ((unsigned)h1 << 16);
                lw_[e] = (unsigned)f2bf(r0) | ((unsigned)f2bf(r1) << 16);
            }
            uint4 uh; uh.x = hw_[0]; uh.y = hw_[1]; uh.z = hw_[2]; uh.w = hw_[3];
            uint4 ul; ul.x = lw_[0]; ul.y = lw_[1]; ul.z = lw_[2]; ul.w = lw_[3];
            *(uint4*)(pb + (((s + rot) & 7) * 16)) = uh;
            *(uint4*)(pb + (((s + 4 + rot) & 7) * 16)) = ul;
        }
    }
    float s1[4] = {0, 0, 0, 0}, s2[4] = {0, 0, 0, 0};
#pragma unroll
    for (int co = 0; co < 32; ++co) {
        float v = acc[co];
        s1[co >> 3] += v;
        s2[co >> 3] = fmaf(v, v, s2[co >> 3]);
    }
#pragma unroll
    for (int off = 32; off > 0; off >>= 1) {
#pragma unroll
        for (int g = 0; g < 4; ++g) {
            s1[g] += __shfl_down(s1[g], off);
            s2[g] += __shfl_down(s2[g], off);
        }
    }
    if ((tid & 63) == 0) {
#pragma unroll
        for (int g = 0; g < 4; ++g) {
            sRed[wid][g] = s1[g];
            sRed[wid][4 + g] = s2[g];
        }
    }
    __syncthreads();
    if (tid < 8) {
        float t = sRed[0][tid] + sRed[1][tid] + sRed[2][tid] + sRed[3][tid];
        statp[((size_t)b * 16 + strip) * 8 + tid] = t;
    }
}

// ---------------------------------------------------------------------------
// GN finalize: per-strip stats -> per-(b,c) affine coefs  y = a*x + b
// ---------------------------------------------------------------------------
__global__ __launch_bounds__(256) void gn_finalize_kernel(
    const float* __restrict__ statp, const float* __restrict__ gma,
    const float* __restrict__ bta, float* __restrict__ coef, int n) {
    int i = blockIdx.x * 256 + threadIdx.x;
    if (i >= n) return;
    int b = i >> 5, c = i & 31, g = c >> 3;
    float s1 = 0.0f, s2 = 0.0f;
    for (int s = 0; s < 16; ++s) {
        s1 += statp[((size_t)b * 16 + s) * 8 + g];
        s2 += statp[((size_t)b * 16 + s) * 8 + 4 + g];
    }
    const float invN = 1.0f / 32768.0f;
    float mean = s1 * invN;
    float var = s2 * invN - mean * mean;
    float rstd = rsqrtf(var + 1e-5f);
    float a = rstd * gma[c];
    float bb = bta[c] - mean * a;
    coef[i * 2 + 0] = a;
    coef[i * 2 + 1] = bb;
}

// ---------------------------------------------------------------------------
// MFMA 3x3 conv with FUSED input GN+GELU, CIN=COUT=32, split-bf16 3-term.
// Epilogue: pack (h|l<<16) u32 per value into LDS transpose [256px][34]
// (pad 2 -> 2-way bank alias, free), then 2 px/thread re-read + 8 coalesced
// uint4 stores per pixel.  Writes raw Q + per-strip GN stats.
// ---------------------------------------------------------------------------
__global__ __launch_bounds__(128) void convm_kernel(
    const unsigned short* __restrict__ qin, const float* __restrict__ coef,
    const unsigned short* __restrict__ wq,
    unsigned short* __restrict__ qout, float* __restrict__ statp) {
    const int b = blockIdx.y;
    const int strip = blockIdx.x;
    const int tid = threadIdx.x;
    const int wv = tid >> 6;
    const int lane = tid & 63;
    const int m = lane & 31;
    const int hf = lane >> 5;
    const int xh32 = wv * 32;

    __shared__ __align__(16) char sQ[6 * 8448];
    __shared__ float sRed[2][8];

    const int y0 = strip * 4;
    const char* img = (const char*)qin + (size_t)b * HW * 128;

    // per-thread coefs for its fixed sub-block (8 channels)
    const int s_id = tid & 3;
    float ca[8], cb[8];
#pragma unroll
    for (int e = 0; e < 8; ++e) {
        ca[e] = coef[b * 64 + (s_id * 8 + e) * 2 + 0];
        cb[e] = coef[b * 64 + (s_id * 8 + e) * 2 + 1];
    }

#pragma unroll
    for (int it = 0; it < 12; ++it) {
        int idx = it * 128 + tid;
        int r = idx >> 8;             // 0..5
        int px = (idx >> 2) & 63;     // pixel in row
        int gy = y0 - 1 + r;
        int rot = px & 7;
        int offH = ((s_id + rot) & 7) * 16;
        int offL = ((s_id + 4 + rot) & 7) * 16;
        char* dst = sQ + r * 8448 + 128 + px * 128;
        uint4 oh, ol;
        if (gy >= 0 && gy < 64) {
            const char* src = img + (size_t)gy * 8192 + px * 128;
            uint4 uhv = *(const uint4*)(src + offH);
            uint4 ulv = *(const uint4*)(src + offL);
            unsigned int hd[4] = {uhv.x, uhv.y, uhv.z, uhv.w};
            unsigned int ld[4] = {ulv.x, ulv.y, ulv.z, ulv.w};
            unsigned int ho[4], lo_[4];
#pragma unroll
            for (int e = 0; e < 4; ++e) {
                float x0 = bf2f((unsigned short)(hd[e] & 0xFFFF)) + bf2f((unsigned short)(ld[e] & 0xFFFF));
                float x1 = bf2f((unsigned short)(hd[e] >> 16)) + bf2f((unsigned short)(ld[e] >> 16));
                float y0v = gelu_f(fmaf(ca[e * 2], x0, cb[e * 2]));
                float y1v = gelu_f(fmaf(ca[e * 2 + 1], x1, cb[e * 2 + 1]));
                unsigned short h0 = f2bf(y0v), h1 = f2bf(y1v);
                unsigned short l0 = f2bf(y0v - bf2f(h0)), l1 = f2bf(y1v - bf2f(h1));
                ho[e] = (unsigned)h0 | ((unsigned)h1 << 16);
                lo_[e] = (unsigned)l0 | ((unsigned)l1 << 16);
            }
            oh.x = ho[0]; oh.y = ho[1]; oh.z = ho[2]; oh.w = ho[3];
            ol.x = lo_[0]; ol.y = lo_[1]; ol.z = lo_[2]; ol.w = lo_[3];
        } else {
            oh.x = oh.y = oh.z = oh.w = 0;
            ol.x = ol.y = ol.z = ol.w = 0;
        }
        *(uint4*)(dst + offH) = oh;
        *(uint4*)(dst + offL) = ol;
    }
    if (tid < 96) {
        int pb_ = tid >> 3, sub = tid & 7;
        int r = pb_ >> 1, side = pb_ & 1;
        uint4 z; z.x = z.y = z.z = z.w = 0;
        *(uint4*)(sQ + r * 8448 + side * 8320 + sub * 16) = z;
    }
    __syncthreads();

    f32x16_t acc[4];
#pragma unroll
    for (int i = 0; i < 4; ++i)
#pragma unroll
        for (int j = 0; j < 16; ++j) acc[i][j] = 0.0f;

    for (int kx = 0; kx < 3; ++kx) {
        bf16x8_t Wf[3][2][2];  // [ky][kstep][hl]
#pragma unroll
        for (int ky = 0; ky < 3; ++ky)
#pragma unroll
            for (int k2 = 0; k2 < 2; ++k2)
#pragma unroll
                for (int hl = 0; hl < 2; ++hl) {
                    int fi = ((ky * 3 + kx) * 2 + k2) * 2 + hl;
                    Wf[ky][k2][hl] = __builtin_bit_cast(
                        bf16x8_t, *(const uint4*)(wq + (size_t)fi * 512 + lane * 8));
                }
        const int slotb = xh32 + kx + m;
        const int rot = (m + kx + 7) & 7;
#pragma unroll
        for (int li = 0; li < 6; ++li) {
            const char* rowp = sQ + li * 8448 + slotb * 128;
            bf16x8_t Ah[2], Al[2];
#pragma unroll
            for (int k2 = 0; k2 < 2; ++k2) {
                int sh = k2 * 2 + hf;
                Ah[k2] = __builtin_bit_cast(bf16x8_t, *(const uint4*)(rowp + ((sh + rot) & 7) * 16));
                Al[k2] = __builtin_bit_cast(bf16x8_t, *(const uint4*)(rowp + ((sh + 4 + rot) & 7) * 16));
            }
#pragma unroll
            for (int ky = 0; ky < 3; ++ky) {
                int orow = li - ky;
                if (orow < 0 || orow > 3) continue;
#pragma unroll
                for (int k2 = 0; k2 < 2; ++k2) {
                    acc[orow] = __builtin_amdgcn_mfma_f32_32x32x16_bf16(Ah[k2], Wf[ky][k2][0], acc[orow], 0, 0, 0);
                    acc[orow] = __builtin_amdgcn_mfma_f32_32x32x16_bf16(Ah[k2], Wf[ky][k2][1], acc[orow], 0, 0, 0);
                    acc[orow] = __builtin_amdgcn_mfma_f32_32x32x16_bf16(Al[k2], Wf[ky][k2][0], acc[orow], 0, 0, 0);
                }
            }
        }
    }

    // ---- epilogue: stats + LDS transpose (reuse sQ) + coalesced stores
    __syncthreads();  // all MFMA reads of sQ complete
    unsigned int* lds_t = (unsigned int*)sQ;  // [256 px][34] u32 (pad 2)
    const int co = lane & 31;
    float s1 = 0.0f, s2 = 0.0f;
#pragma unroll
    for (int orow = 0; orow < 4; ++orow) {
#pragma unroll
        for (int r = 0; r < 16; ++r) {
            int mm = (r & 3) + 8 * (r >> 2) + 4 * hf;
            int px = (orow << 6) + xh32 + mm;
            float v = acc[orow][r];
            s1 += v;
            s2 = fmaf(v, v, s2);
            unsigned short hv = f2bf(v);
            unsigned short lv = f2bf(v - bf2f(hv));
            lds_t[px * 34 + co] = (unsigned)hv | ((unsigned)lv << 16);
        }
    }
    s1 += __shfl_xor(s1, 32); s2 += __shfl_xor(s2, 32);
    s1 += __shfl_xor(s1, 1);  s2 += __shfl_xor(s2, 1);
    s1 += __shfl_xor(s1, 2);  s2 += __shfl_xor(s2, 2);
    s1 += __shfl_xor(s1, 4);  s2 += __shfl_xor(s2, 4);
    if (lane < 32 && (lane & 7) == 0) {
        sRed[wv][co >> 3] = s1;
        sRed[wv][4 + (co >> 3)] = s2;
    }
    __syncthreads();
    if (tid < 8) statp[((size_t)b * 16 + strip) * 8 + tid] = sRed[0][tid] + sRed[1][tid];

    const char* obb = (const char*)qout;
    char* ob = (char*)qout + ((size_t)b * HW + (size_t)y0 * 64) * 128;
    (void)obb;
#pragma unroll
    for (int pi = 0; pi < 2; ++pi) {
        int p = pi * 128 + tid;          // 0..255
        int rot = p & 7;
        char* pb = ob + (size_t)p * 128;
#pragma unroll
        for (int s = 0; s < 4; ++s) {
            unsigned int hw_[4], lw_[4];
#pragma unroll
            for (int j = 0; j < 4; ++j) {
                int c0 = s * 8 + j * 2;
                uint2 t2 = *(const uint2*)(lds_t + p * 34 + c0);
                hw_[j] = (t2.x & 0xFFFFu) | (t2.y << 16);
                lw_[j] = (t2.x >> 16) | (t2.y & 0xFFFF0000u);
            }
            uint4 uh; uh.x = hw_[0]; uh.y = hw_[1]; uh.z = hw_[2]; uh.w = hw_[3];
            uint4 ul; ul.x = lw_[0]; ul.y = lw_[1]; ul.z = lw_[2]; ul.w = lw_[3];
            *(uint4*)(pb + (((s + rot) & 7) * 16)) = uh;
            *(uint4*)(pb + (((s + 4 + rot) & 7) * 16)) = ul;
        }
    }
}

// ---------------------------------------------------------------------------
// Projection + l2norm + FUSED gauss-pool partials from RAW Q (GN+GELU on read).
// Writes bf16 NCHW planes, poolp[b][chunk][32] partials (+E, swp for rubin).
// ---------------------------------------------------------------------------
__global__ __launch_bounds__(256) void proj_kernel(
    const unsigned short* __restrict__ q, const float* __restrict__ coef,
    const float* __restrict__ pw, unsigned short* __restrict__ outn,
    float* __restrict__ poolp, float* __restrict__ E, float* __restrict__ swp,
    const float* __restrict__ gauss) {
    int b = blockIdx.y, chunk = blockIdx.x, tid = threadIdx.x;
    int p = chunk * 256 + tid;
    __shared__ float sR[4];
    __shared__ float sc[64];
    __shared__ float red[32][257];
    if (tid < 64) sc[tid] = coef[b * 64 + tid];
    __syncthreads();
    float feat[32];
    {
        int rot = p & 7;
        const char* pb = (const char*)q + (((size_t)b * HW) + p) * 128;
#pragma unroll
        for (int s = 0; s < 4; ++s) {
            uint4 uh = *(const uint4*)(pb + (((s + rot) & 7) * 16));
            uint4 ul = *(const uint4*)(pb + (((s + 4 + rot) & 7) * 16));
            unsigned int hd[4] = {uh.x, uh.y, uh.z, uh.w};
            unsigned int ld[4] = {ul.x, ul.y, ul.z, ul.w};
#pragma unroll
            for (int e = 0; e < 4; ++e) {
                int c0 = s * 8 + e * 2;
                float x0 = bf2f((unsigned short)(hd[e] & 0xFFFF)) + bf2f((unsigned short)(ld[e] & 0xFFFF));
                float x1 = bf2f((unsigned short)(hd[e] >> 16)) + bf2f((unsigned short)(ld[e] >> 16));
                feat[c0] = gelu_f(fmaf(sc[c0 * 2], x0, sc[c0 * 2 + 1]));
                feat[c0 + 1] = gelu_f(fmaf(sc[(c0 + 1) * 2], x1, sc[(c0 + 1) * 2 + 1]));
            }
        }
    }
    // pool partial staging
    float g = gauss[p];
#pragma unroll
    for (int c = 0; c < 32; ++c) red[c][tid] = feat[c] * g;

    float o[32];
#pragma unroll
    for (int oo = 0; oo < 32; ++oo) o[oo] = 0.0f;
    for (int c = 0; c < 32; ++c) {
        float f = feat[c];
#pragma unroll
        for (int oo = 0; oo < 32; ++oo) o[oo] = fmaf(pw[oo * 32 + c], f, o[oo]);
    }
    float nn = 0.0f;
#pragma unroll
    for (int oo = 0; oo < 32; ++oo) nn = fmaf(o[oo], o[oo], nn);
    float n = sqrtf(nn);
    float inv = 1.0f / fmaxf(n, 1e-6f);
    unsigned short* obp = outn + (size_t)b * 32 * HW + p;
#pragma unroll
    for (int oo = 0; oo < 32; ++oo) obp[(size_t)oo * HW] = f2bf(o[oo] * inv);

    __syncthreads();
    if (tid < 32) {
        float s = 0.0f;
#pragma unroll 8
        for (int i = 0; i < 256; ++i) s += red[tid][i];
        poolp[((size_t)b * 16 + chunk) * 32 + tid] = s;
    }

    if (E != nullptr) {
        float e = nn * inv * inv;
        E[(size_t)b * HW + p] = e;
        float wvv = e * g;
#pragma unroll
        for (int off = 32; off > 0; off >>= 1) wvv += __shfl_down(wvv, off);
        if ((tid & 63) == 0) sR[tid >> 6] = wvv;
        __syncthreads();
        if (tid == 0) swp[b * 16 + chunk] = sR[0] + sR[1] + sR[2] + sR[3];
    }
}

// ---------------------------------------------------------------------------
// E <- E * gauss * scale / (sum_p(E*gauss) + 1e-8)
// ---------------------------------------------------------------------------
__global__ __launch_bounds__(256) void swapply_kernel(
    float* __restrict__ E, const float* __restrict__ swp,
    const float* __restrict__ gauss) {
    int b = blockIdx.y, p = blockIdx.x * 256 + threadIdx.x;
    float s = 0.0f;
#pragma unroll
    for (int i = 0; i < 16; ++i) s += swp[b * 16 + i];
    const float scale = 0.17677669529663688f;
    E[(size_t)b * HW + p] = E[(size_t)b * HW + p] * gauss[p] * scale / (s + 1e-8f);
}

// ---------------------------------------------------------------------------
// 49-offset correlation logits, channel-split: grid (bc, 8).
// ---------------------------------------------------------------------------
__global__ __launch_bounds__(256) void logits_kernel(
    const unsigned short* __restrict__ rn, const unsigned short* __restrict__ vn,
    const float* __restrict__ sw, float* __restrict__ lgpart) {
    int b = blockIdx.x, cg = blockIdx.y, tid = threadIdx.x;
    __shared__ float P[38][76];
    __shared__ float sR[4][49];
    float acc[49];
#pragma unroll
    for (int k = 0; k < 49; ++k) acc[k] = 0.0f;
    const float* swb = sw + (size_t)b * HW;
#pragma unroll 1
    for (int cc = 0; cc < 4; ++cc) {
        int c = cg * 4 + cc;
        const unsigned short* vb = vn + ((size_t)b * 32 + c) * HW;
        const unsigned short* rb = rn + ((size_t)b * 32 + c) * HW;
#pragma unroll 1
        for (int half = 0; half < 2; ++half) {
            const int base = half * 32;
            __syncthreads();
            for (int idx = tid; idx < 38 * 72; idx += 256) {
                int r = idx / 72, j = idx - r * 72;
                int gy = base - 3 + r;
                gy = gy < 0 ? 0 : (gy > 63 ? 63 : gy);
                int gx = j - 4;
                gx = gx < 0 ? 0 : (gx > 63 ? 63 : gx);
                P[r][j] = bf2f(vb[gy * 64 + gx]);
            }
            __syncthreads();
            int y = tid >> 3, x0 = (tid & 7) * 8;
            int pbase = (base + y) * 64 + x0;
            uint4 rv = *(const uint4*)(rb + pbase);
            float4 q0 = *(const float4*)(swb + pbase);
            float4 q1 = *(const float4*)(swb + pbase + 4);
            unsigned int rd[4] = {rv.x, rv.y, rv.z, rv.w};
            float r_[8];
            r_[0] = bf2f((unsigned short)(rd[0] & 0xFFFF)) * q0.x;
            r_[1] = bf2f((unsigned short)(rd[0] >> 16)) * q0.y;
            r_[2] = bf2f((unsigned short)(rd[1] & 0xFFFF)) * q0.z;
            r_[3] = bf2f((unsigned short)(rd[1] >> 16)) * q0.w;
            r_[4] = bf2f((unsigned short)(rd[2] & 0xFFFF)) * q1.x;
            r_[5] = bf2f((unsigned short)(rd[2] >> 16)) * q1.y;
            r_[6] = bf2f((unsigned short)(rd[3] & 0xFFFF)) * q1.z;
            r_[7] = bf2f((unsigned short)(rd[3] >> 16)) * q1.w;
#pragma unroll
            for (int dy = 0; dy < 7; ++dy) {
                const float4* Pr = (const float4*)(&P[y + dy][x0]);
                float4 a0 = Pr[0], a1 = Pr[1], a2 = Pr[2], a3 = Pr[3];
                float v[16] = {a0.x, a0.y, a0.z, a0.w, a1.x, a1.y, a1.z, a1.w,
                               a2.x, a2.y, a2.z, a2.w, a3.x, a3.y, a3.z, a3.w};
#pragma unroll
                for (int dx = 0; dx < 7; ++dx) {
#pragma unroll
                    for (int j = 0; j < 8; ++j)
                        acc[dy * 7 + dx] = fmaf(r_[j], v[j + dx + 1], acc[dy * 7 + dx]);
                }
            }
        }
    }
#pragma unroll
    for (int k = 0; k < 49; ++k) {
#pragma unroll
        for (int off = 32; off > 0; off >>= 1) acc[k] += __shfl_down(acc[k], off);
    }
    int wid = tid >> 6;
    __syncthreads();
    if ((tid & 63) == 0) {
#pragma unroll
        for (int k = 0; k < 49; ++k) sR[wid][k] = acc[k];
    }
    __syncthreads();
    if (tid < 49)
        lgpart[((size_t)b * 8 + cg) * 49 + tid] =
            sR[0][tid] + sR[1][tid] + sR[2][tid] + sR[3][tid];
}

// ---------------------------------------------------------------------------
// Softmax/coarse + MLP head + output assembly. Reduces logit & pool partials.
// ---------------------------------------------------------------------------
__global__ __launch_bounds__(128) void head_kernel(
    const float* __restrict__ lg, const float* __restrict__ rpp,
    const float* __restrict__ vpp, const float* __restrict__ p2s,
    const float* __restrict__ log_temp,
    const float* __restrict__ W1, const float* __restrict__ b1,
    const float* __restrict__ W2, const float* __restrict__ b2,
    const float* __restrict__ W3, const float* __restrict__ b3,
    float* __restrict__ out) {
    int b = blockIdx.x, t = threadIdx.x;
    __shared__ float slg[49];
    __shared__ float pooled[98];
    __shared__ float h1[128], h2[128];
    __shared__ float cxy[2];
    __shared__ float res[3];
    const float* lgp = lg + (size_t)b * 8 * 49;
    if (t < 49) {
        float s = 0.0f;
#pragma unroll
        for (int g = 0; g < 8; ++g) s += lgp[g * 49 + t];
        slg[t] = s;
    }
    __syncthreads();
    if (t == 0) {
        float temp = fmaxf(expf(log_temp[0]), 0.001f);
        float invT = 1.0f / temp;
        float m = -1e30f;
        for (int k = 0; k < 49; ++k) m = fmaxf(m, slg[k] * invT);
        float s = 0.0f, pdx = 0.0f, pdy = 0.0f;
        for (int k = 0; k < 49; ++k) {
            float e = expf(slg[k] * invT - m);
            s += e;
            pdx += e * (float)((k % 7) - 3);
            pdy += e * (float)((k / 7) - 3);
        }
        cxy[0] = pdx / s;
        cxy[1] = pdy / s;
    }
    __syncthreads();
    if (t < 32) {
        float a = 0.0f, c = 0.0f;
#pragma unroll
        for (int k = 0; k < 16; ++k) {
            a += rpp[((size_t)b * 16 + k) * 32 + t];
            c += vpp[((size_t)b * 16 + k) * 32 + t];
        }
        pooled[t] = a;
        pooled[32 + t] = c;
        pooled[64 + t] = a - c;
    }
    if (t == 0) {
        pooled[96] = cxy[0];
        pooled[97] = cxy[1];
    }
    __syncthreads();
    float s1 = b1[t];
    for (int i = 0; i < 98; ++i) s1 = fmaf(pooled[i], W1[i * 128 + t], s1);
    h1[t] = gelu_f(s1);
    __syncthreads();
    float s2 = b2[t];
    for (int i = 0; i < 128; ++i) s2 = fmaf(h1[i], W2[i * 128 + t], s2);
    h2[t] = gelu_f(s2);
    __syncthreads();
    if (t < 3) {
        float r = b3[t];
        for (int i = 0; i < 128; ++i) r = fmaf(h2[i], W3[i * 3 + t], r);
        res[t] = r;
    }
    __syncthreads();
    if (t == 0) {
        float dxp = cxy[0] + res[0];
        float dyp = cxy[1] + res[1];
        float ls = fminf(fmaxf(res[2], -6.0f), 3.0f);
        const float* M = p2s + b * 4;
        float* ob = out + b * 54;
        ob[0] = dxp;
        ob[1] = dyp;
        ob[2] = M[0] * dxp + M[1] * dyp;
        ob[3] = M[2] * dxp + M[3] * dyp;
        ob[4] = ls;
    }
    if (t < 49) out[b * 54 + 5 + t] = slg[t];
}

extern "C" void kernel_launch(void* const* d_in, const int* in_sizes, int n_in,
                              void* d_out, int out_size, void* d_ws, size_t ws_size,
                              hipStream_t stream) {
    (void)in_sizes; (void)n_in; (void)out_size;
    const float* rubin = (const float*)d_in[0];
    const float* vis   = (const float*)d_in[1];
    const float* p2s   = (const float*)d_in[2];
    const float* rW0   = (const float*)d_in[3];
    const float* rWs   = (const float*)d_in[4];
    const float* rG    = (const float*)d_in[5];
    const float* rBt   = (const float*)d_in[6];
    const float* vW0   = (const float*)d_in[7];
    const float* vWs   = (const float*)d_in[8];
    const float* vG    = (const float*)d_in[9];
    const float* vBt   = (const float*)d_in[10];
    const float* projR = (const float*)d_in[11];
    const float* projV = (const float*)d_in[12];
    const float* logT  = (const float*)d_in[13];
    const float* W1    = (const float*)d_in[14];
    const float* b1    = (const float*)d_in[15];
    const float* W2    = (const float*)d_in[16];
    const float* b2    = (const float*)d_in[17];
    const float* W3    = (const float*)d_in[18];
    const float* b3    = (const float*)d_in[19];
    float* out = (float*)d_out;

    // ---- workspace layout (bytes)
    char* ws = (char*)d_ws;
    size_t off = 0;
    unsigned short* vnB = (unsigned short*)(ws + off); off += (size_t)NB * 32 * HW * 2;  // 67.1 MB
    float* gauss  = (float*)(ws + off); off += HW * 4;
    float* statp  = (float*)(ws + off); off += (size_t)NB * 16 * 8 * 4;
    float* coefS  = (float*)(ws + off); off += (size_t)NB * 64 * 4;
    float* swp    = (float*)(ws + off); off += (size_t)NB * 16 * 4;
    float* rpp    = (float*)(ws + off); off += (size_t)NB * 16 * 32 * 4;
    float* vpp    = (float*)(ws + off); off += (size_t)NB * 16 * 32 * 4;
    float* lgbuf  = (float*)(ws + off); off += (size_t)NB * 8 * 49 * 4;
    unsigned short* wq = (unsigned short*)(ws + off); off += 110592ull * 2;
    off = (off + 255) & ~(size_t)255;
    const size_t fixed_bytes = off;
    const size_t perb = 2ull * HW * 128 + HW * 4;  // Q1+Q2 pixel blocks + E
    int BC = 1;
    if (ws_size > fixed_bytes + perb) {
        size_t t = (ws_size - fixed_bytes) / perb;
        BC = t > (size_t)NB ? NB : (int)t;
    }
    unsigned short* Q1 = (unsigned short*)(ws + off);
    unsigned short* Q2 = (unsigned short*)(ws + off + (size_t)BC * HW * 128);
    float* E = (float*)(ws + off + 2ull * BC * HW * 128);

    dim3 blk256(256), blk128(128);
    gauss_kernel<<<1, 256, 0, stream>>>(gauss);
    prep_w_kernel<<<432, 256, 0, stream>>>(rWs, vWs, wq);

    // ================= VIS encoder (all chunks) =================
    for (int b0 = 0; b0 < NB; b0 += BC) {
        const int bc = (NB - b0) < BC ? (NB - b0) : BC;
        dim3 cg16(16, bc);
        const int gnblk = (bc * 32 + 255) / 256;
        float* sp = statp + (size_t)b0 * 128;
        float* cS = coefS + (size_t)b0 * 64;

        conv_first_kernel<1><<<cg16, blk256, 0, stream>>>(vis + (size_t)b0 * HW, vW0, Q1, sp);
        gn_finalize_kernel<<<gnblk, 256, 0, stream>>>(sp, vG + 0, vBt + 0, cS, bc * 32);
        convm_kernel<<<cg16, blk128, 0, stream>>>(Q1, cS, wq + 3 * 18432, Q2, sp);
        gn_finalize_kernel<<<gnblk, 256, 0, stream>>>(sp, vG + 32, vBt + 32, cS, bc * 32);
        convm_kernel<<<cg16, blk128, 0, stream>>>(Q2, cS, wq + 4 * 18432, Q1, sp);
        gn_finalize_kernel<<<gnblk, 256, 0, stream>>>(sp, vG + 64, vBt + 64, cS, bc * 32);
        convm_kernel<<<cg16, blk128, 0, stream>>>(Q1, cS, wq + 5 * 18432, Q2, sp);
        gn_finalize_kernel<<<gnblk, 256, 0, stream>>>(sp, vG + 96, vBt + 96, cS, bc * 32);
        proj_kernel<<<cg16, blk256, 0, stream>>>(Q2, cS, projV, vnB + (size_t)b0 * 32 * HW,
                                                 vpp + (size_t)b0 * 512,
                                                 (float*)nullptr, (float*)nullptr, gauss);
    }

    // ================= RUBIN encoder + logits (all chunks) =================
    for (int b0 = 0; b0 < NB; b0 += BC) {
        const int bc = (NB - b0) < BC ? (NB - b0) : BC;
        dim3 cg16(16, bc);
        const int gnblk = (bc * 32 + 255) / 256;
        float* sp = statp + (size_t)b0 * 128;
        float* cS = coefS + (size_t)b0 * 64;
        float* sw = swp + (size_t)b0 * 16;
        unsigned short* rnB = Q1;  // dead after last convm reads it

        conv_first_kernel<6><<<cg16, blk256, 0, stream>>>(rubin + (size_t)b0 * 6 * HW, rW0, Q1, sp);
        gn_finalize_kernel<<<gnblk, 256, 0, stream>>>(sp, rG + 0, rBt + 0, cS, bc * 32);
        convm_kernel<<<cg16, blk128, 0, stream>>>(Q1, cS, wq + 0 * 18432, Q2, sp);
        gn_finalize_kernel<<<gnblk, 256, 0, stream>>>(sp, rG + 32, rBt + 32, cS, bc * 32);
        convm_kernel<<<cg16, blk128, 0, stream>>>(Q2, cS, wq + 1 * 18432, Q1, sp);
        gn_finalize_kernel<<<gnblk, 256, 0, stream>>>(sp, rG + 64, rBt + 64, cS, bc * 32);
        convm_kernel<<<cg16, blk128, 0, stream>>>(Q1, cS, wq + 2 * 18432, Q2, sp);
        gn_finalize_kernel<<<gnblk, 256, 0, stream>>>(sp, rG + 96, rBt + 96, cS, bc * 32);
        proj_kernel<<<cg16, blk256, 0, stream>>>(Q2, cS, projR, rnB,
                                                 rpp + (size_t)b0 * 512, E, sw, gauss);
        swapply_kernel<<<cg16, blk256, 0, stream>>>(E, sw, gauss);
        logits_kernel<<<dim3(bc, 8), blk256, 0, stream>>>(rnB, vnB + (size_t)b0 * 32 * HW, E,
                                                          lgbuf + (size_t)b0 * 8 * 49);
    }

    head_kernel<<<NB, 128, 0, stream>>>(lgbuf, rpp, vpp, p2s, logT, W1, b1, W2, b2, W3, b3, out);
}